// Round 1
// baseline (322.257 us; speedup 1.0000x reference)
//
#include <hip/hip_runtime.h>

#define EQN 10

// Block-wide sum reduction for blockDim.x = 1024 (16 waves). red[] must hold 17 floats.
__device__ __forceinline__ float block_reduce(float v, float* red) {
  #pragma unroll
  for (int o = 32; o >= 1; o >>= 1) v += __shfl_xor(v, o, 64);
  const int wid = threadIdx.x >> 6;
  const int lane = threadIdx.x & 63;
  const int nw = blockDim.x >> 6;
  if (lane == 0) red[wid] = v;
  __syncthreads();
  if (wid == 0) {
    float s = (lane < nw) ? red[lane] : 0.f;
    #pragma unroll
    for (int o = 8; o >= 1; o >>= 1) s += __shfl_xor(s, o, 64);
    if (lane == 0) red[16] = s;
  }
  __syncthreads();
  return red[16];
}

// Direct 3x3 SAME conv on 16x16 images. One (n, c_out) plane per 256-thread block.
// act: 0=none, 1=leaky_relu(0.01), 2=sigmoid
__global__ __launch_bounds__(256) void k_conv3x3(
    const float* __restrict__ in, const float* __restrict__ w,
    const float* __restrict__ bias, float* __restrict__ out,
    int Cin, int Cout, int act) {
  const int n = blockIdx.x / Cout;
  const int co = blockIdx.x % Cout;
  const int t = threadIdx.x;
  const int x = t & 15, y = t >> 4;
  __shared__ float tile[16 * 256];
  const float* inb = in + n * Cin * 256;
  const float* wb = w + co * Cin * 9;
  float acc = bias[co];
  for (int c0 = 0; c0 < Cin; c0 += 16) {
    #pragma unroll
    for (int k = 0; k < 16; ++k) tile[k * 256 + t] = inb[(c0 + k) * 256 + t];
    __syncthreads();
    for (int k = 0; k < 16; ++k) {
      const float* wk = wb + (c0 + k) * 9;
      const float* tl = tile + k * 256;
      float a = wk[4] * tl[t];
      if (y > 0) {
        a += wk[1] * tl[t - 16];
        if (x > 0) a += wk[0] * tl[t - 17];
        if (x < 15) a += wk[2] * tl[t - 15];
      }
      if (x > 0) a += wk[3] * tl[t - 1];
      if (x < 15) a += wk[5] * tl[t + 1];
      if (y < 15) {
        a += wk[7] * tl[t + 16];
        if (x > 0) a += wk[6] * tl[t + 15];
        if (x < 15) a += wk[8] * tl[t + 17];
      }
      acc += a;
    }
    __syncthreads();
  }
  if (act == 1) acc = acc > 0.f ? acc : 0.01f * acc;
  else if (act == 2) acc = 1.f / (1.f + __expf(-acc));
  out[(n * Cout + co) * 256 + t] = acc;
}

// SE branch: global-avg-pool -> 1x1 conv (64->32) lrelu -> 1x1 conv (32->16) sigmoid.
__global__ __launch_bounds__(256) void k_se(
    const float* __restrict__ x, const float* __restrict__ w1, const float* __restrict__ b1,
    const float* __restrict__ w2, const float* __restrict__ b2, float* __restrict__ se) {
  const int n = blockIdx.x;
  const int t = threadIdx.x;
  __shared__ float pooled[64];
  __shared__ float h1[32];
  const int c = t >> 2, part = t & 3;
  const float* xp = x + (n * 64 + c) * 256 + part * 64;
  float s = 0.f;
  for (int k = 0; k < 64; ++k) s += xp[k];
  s += __shfl_xor(s, 1, 64);
  s += __shfl_xor(s, 2, 64);
  if (part == 0) pooled[c] = s * (1.f / 256.f);
  __syncthreads();
  if (t < 32) {
    float a = b1[t];
    for (int k = 0; k < 64; ++k) a += w1[t * 64 + k] * pooled[k];
    h1[t] = a > 0.f ? a : 0.01f * a;
  }
  __syncthreads();
  if (t < 16) {
    float a = b2[t];
    for (int k = 0; k < 32; ++k) a += w2[t * 32 + k] * h1[k];
    se[n * 16 + t] = 1.f / (1.f + __expf(-a));
  }
}

// Jacobi-preconditioned CG on the sparse normal equations.
// ATA is a weighted graph Laplacian over 1024 nodes (4 fields x 256 pixels),
// max degree 5, anchored at the last pixel of each field (SPD).
// One block (1024 threads) per system b in [0,16); thread j owns node (f=j>>8, i=j&255).
__global__ __launch_bounds__(1024) void k_pcg(
    const float* __restrict__ att, const float* __restrict__ grad,
    float* __restrict__ sol, int maxit, float tol2) {
  const int b = blockIdx.x;
  const int n = b >> 2, g = b & 3;
  const int j = threadIdx.x;
  const int f = j >> 8;
  const int i = j & 255;
  const int px = i & 15, py = i >> 4;
  __shared__ float Wl[EQN * 256];  // att^2 per (eqn, pixel)
  __shared__ float Cl[EQN * 256];  // att^2 * grad per (eqn, pixel)
  __shared__ float pl[1024];       // CG direction vector
  __shared__ float red[17];
  const float* ab = att + (n * 40 + g * 10) * 256;
  const float* gb = grad + (n * 40 + g * 10) * 256;
  for (int idx = j; idx < EQN * 256; idx += 1024) {
    float a = ab[idx];
    float w = a * a;
    Wl[idx] = w;
    Cl[idx] = w * gb[idx];
  }
  __syncthreads();

  // Per-field right/down equation indices (f is wave-uniform: 64 | 256).
  int er, ed;
  if (f == 0)      { er = 4; ed = 9; }
  else if (f == 1) { er = 8; ed = 5; }
  else if (f == 2) { er = 2; ed = 7; }
  else             { er = 6; ed = 3; }

  float diag = 1e-12f, rhs = 0.f;
  int n0 = j, n1 = j, n2 = j, n3 = j, n4 = j;  // absent neighbors -> self with weight 0
  float w0 = 0.f, w1 = 0.f, w2 = 0.f, w3 = 0.f, w4 = 0.f;
  const int fb = f << 8;
  if (px < 15) { w0 = Wl[er * 256 + i];      n0 = fb + i + 1;  diag += w0; rhs += Cl[er * 256 + i]; }
  if (px > 0)  { w1 = Wl[er * 256 + i - 1];  n1 = fb + i - 1;  diag += w1; rhs -= Cl[er * 256 + i - 1]; }
  if (py < 15) { w2 = Wl[ed * 256 + i];      n2 = fb + i + 16; diag += w2; rhs += Cl[ed * 256 + i]; }
  if (py > 0)  { w3 = Wl[ed * 256 + i - 16]; n3 = fb + i - 16; diag += w3; rhs -= Cl[ed * 256 + i - 16]; }
  // Cross-field edges: e0: F2_i -- F0_{i+1}; e1: F3_i -- F1_{i+16}
  if (f == 0) {
    if (px > 0)  { w4 = Wl[0 * 256 + i - 1];  n4 = (2 << 8) + i - 1;  diag += w4; rhs -= Cl[0 * 256 + i - 1]; }
  } else if (f == 1) {
    if (py > 0)  { w4 = Wl[1 * 256 + i - 16]; n4 = (3 << 8) + i - 16; diag += w4; rhs -= Cl[1 * 256 + i - 16]; }
  } else if (f == 2) {
    if (px < 15) { w4 = Wl[0 * 256 + i];      n4 = (0 << 8) + i + 1;  diag += w4; rhs += Cl[0 * 256 + i]; }
  } else {
    if (py < 15) { w4 = Wl[1 * 256 + i];      n4 = (1 << 8) + i + 16; diag += w4; rhs += Cl[1 * 256 + i]; }
  }
  // Anchor rows at the last pixel (single +1 entries -> diagonal + rhs only).
  if (i == 255) {
    if (f == 0)      { diag += Wl[4*256+255] + Wl[9*256+255]; rhs += Cl[4*256+255] + Cl[9*256+255]; }
    else if (f == 1) { diag += Wl[5*256+255] + Wl[8*256+255]; rhs += Cl[5*256+255] + Cl[8*256+255]; }
    else if (f == 2) { diag += Wl[0*256+255] + Wl[2*256+255] + Wl[7*256+255];
                       rhs  += Cl[0*256+255] + Cl[2*256+255] + Cl[7*256+255]; }
    else             { diag += Wl[1*256+255] + Wl[3*256+255] + Wl[6*256+255];
                       rhs  += Cl[1*256+255] + Cl[3*256+255] + Cl[6*256+255]; }
  }

  const float invd = 1.f / diag;
  float xv = 0.f, r = rhs;
  float z = r * invd;
  float p = z;
  pl[j] = p;
  float rz = block_reduce(r * z, red);  // barriers inside make pl visible
  const float thresh = tol2 * rz;
  for (int it = 0; it < maxit && rz > thresh; ++it) {
    float q = diag * p - (w0 * pl[n0] + w1 * pl[n1] + w2 * pl[n2] + w3 * pl[n3] + w4 * pl[n4]);
    float pq = block_reduce(p * q, red);
    float alpha = rz / pq;
    xv += alpha * p;
    r -= alpha * q;
    z = r * invd;
    float rznew = block_reduce(r * z, red);
    float beta = rznew / rz;
    rz = rznew;
    p = z + beta * p;
    pl[j] = p;            // safe: all SpMV reads done before pq-reduce barrier
    __syncthreads();      // make new p visible before next SpMV
  }
  sol[b * 1024 + j] = xv;
}

// GroupNorm(1, 16) per sample over all 16*256 values + gn affine + SE scale.
// sol[b=n*4+g][f*256+pix] -> y[n][c=g*4+f][pix]
__global__ __launch_bounds__(1024) void k_norm(
    const float* __restrict__ sol, const float* __restrict__ se,
    const float* __restrict__ gn_w, const float* __restrict__ gn_b,
    float* __restrict__ out) {
  const int n = blockIdx.x;
  const int t = threadIdx.x;
  __shared__ float red[17];
  float v[4];
  float s = 0.f, s2 = 0.f;
  #pragma unroll
  for (int k = 0; k < 4; ++k) {
    int idx = t + k * 1024;
    int c = idx >> 8, pix = idx & 255;
    int g = c >> 2, ff = c & 3;
    float val = sol[(n * 4 + g) * 1024 + ff * 256 + pix];
    v[k] = val; s += val; s2 += val * val;
  }
  s = block_reduce(s, red);
  s2 = block_reduce(s2, red);
  float mu = s * (1.f / 4096.f);
  float var = s2 * (1.f / 4096.f) - mu * mu;
  float rstd = rsqrtf(var + 1e-5f);
  #pragma unroll
  for (int k = 0; k < 4; ++k) {
    int idx = t + k * 1024;
    int c = idx >> 8;
    float yv = (v[k] - mu) * rstd * gn_w[c] + gn_b[c];
    yv *= se[n * 16 + c];
    out[n * 4096 + idx] = yv;
  }
}

extern "C" void kernel_launch(void* const* d_in, const int* in_sizes, int n_in,
                              void* d_out, int out_size, void* d_ws, size_t ws_size,
                              hipStream_t stream) {
  const float* x       = (const float*)d_in[0];
  const float* grad_w1 = (const float*)d_in[1];
  const float* grad_b1 = (const float*)d_in[2];
  const float* grad_w2 = (const float*)d_in[3];
  const float* grad_b2 = (const float*)d_in[4];
  const float* att_w1  = (const float*)d_in[5];
  const float* att_b1  = (const float*)d_in[6];
  const float* att_w2  = (const float*)d_in[7];
  const float* att_b2  = (const float*)d_in[8];
  const float* se_w1   = (const float*)d_in[9];
  const float* se_b1   = (const float*)d_in[10];
  const float* se_w2   = (const float*)d_in[11];
  const float* se_b2   = (const float*)d_in[12];
  const float* gn_w    = (const float*)d_in[13];
  const float* gn_b    = (const float*)d_in[14];
  const float* post_w  = (const float*)d_in[15];
  const float* post_b  = (const float*)d_in[16];
  float* out = (float*)d_out;
  float* ws = (float*)d_ws;

  // Workspace layout (floats). t1 is reused for sol+ynorm after the att branch finishes.
  float* t1    = ws;               // 65536 = 4*64*256 (conv1 output, both branches)
  float* gradb = ws + 65536;       // 40960 = 4*40*256
  float* attb  = ws + 106496;      // 40960
  float* seb   = ws + 147456;      // 64
  float* solb  = ws;               // 16384 (reuses t1)
  float* ynorm = ws + 16384;       // 16384 (reuses t1)

  k_conv3x3<<<4 * 64, 256, 0, stream>>>(x, grad_w1, grad_b1, t1, 64, 64, 1);
  k_conv3x3<<<4 * 40, 256, 0, stream>>>(t1, grad_w2, grad_b2, gradb, 64, 40, 0);
  k_conv3x3<<<4 * 64, 256, 0, stream>>>(x, att_w1, att_b1, t1, 64, 64, 1);
  k_conv3x3<<<4 * 40, 256, 0, stream>>>(t1, att_w2, att_b2, attb, 64, 40, 2);
  k_se<<<4, 256, 0, stream>>>(x, se_w1, se_b1, se_w2, se_b2, seb);
  k_pcg<<<16, 1024, 0, stream>>>(attb, gradb, solb, 3000, 1e-10f);
  k_norm<<<4, 1024, 0, stream>>>(solb, seb, gn_w, gn_b, ynorm);
  k_conv3x3<<<4 * 128, 256, 0, stream>>>(ynorm, post_w, post_b, out, 16, 128, 0);
}

// Round 2
// 184.641 us; speedup vs baseline: 1.7453x; 1.7453x over previous
//
#include <hip/hip_runtime.h>

// ---------------------------------------------------------------------------
// Dual-branch direct 3x3 SAME conv on 16x16 images (grad + att branches in one
// dispatch). One (branch, n, c_out) plane per 256-thread block.
// act: 0=none, 1=leaky_relu(0.01), 2=sigmoid
// ---------------------------------------------------------------------------
__global__ __launch_bounds__(256) void k_conv3x3_dual(
    const float* __restrict__ in_a, const float* __restrict__ in_b,
    const float* __restrict__ w_a, const float* __restrict__ bias_a,
    const float* __restrict__ w_b, const float* __restrict__ bias_b,
    float* __restrict__ out_a, float* __restrict__ out_b,
    int Cin, int Cout, int act_a, int act_b) {
  int nc = blockIdx.x;
  const int half = gridDim.x >> 1;
  const int br = nc >= half ? 1 : 0;
  if (br) nc -= half;
  const float* in = br ? in_b : in_a;
  const float* w = br ? w_b : w_a;
  const float* bias = br ? bias_b : bias_a;
  float* out = br ? out_b : out_a;
  const int act = br ? act_b : act_a;

  const int n = nc / Cout;
  const int co = nc % Cout;
  const int t = threadIdx.x;
  const int x = t & 15, y = t >> 4;
  __shared__ float tile[16 * 256];
  const float* inb = in + n * Cin * 256;
  const float* wb = w + co * Cin * 9;
  float acc = bias[co];
  for (int c0 = 0; c0 < Cin; c0 += 16) {
    #pragma unroll
    for (int k = 0; k < 16; ++k) tile[k * 256 + t] = inb[(c0 + k) * 256 + t];
    __syncthreads();
    for (int k = 0; k < 16; ++k) {
      const float* wk = wb + (c0 + k) * 9;
      const float* tl = tile + k * 256;
      float a = wk[4] * tl[t];
      if (y > 0) {
        a += wk[1] * tl[t - 16];
        if (x > 0) a += wk[0] * tl[t - 17];
        if (x < 15) a += wk[2] * tl[t - 15];
      }
      if (x > 0) a += wk[3] * tl[t - 1];
      if (x < 15) a += wk[5] * tl[t + 1];
      if (y < 15) {
        a += wk[7] * tl[t + 16];
        if (x > 0) a += wk[6] * tl[t + 15];
        if (x < 15) a += wk[8] * tl[t + 17];
      }
      acc += a;
    }
    __syncthreads();
  }
  if (act == 1) acc = acc > 0.f ? acc : 0.01f * acc;
  else if (act == 2) acc = 1.f / (1.f + __expf(-acc));
  out[(n * Cout + co) * 256 + t] = acc;
}

// Single-branch conv (post conv).
__global__ __launch_bounds__(256) void k_conv3x3(
    const float* __restrict__ in, const float* __restrict__ w,
    const float* __restrict__ bias, float* __restrict__ out,
    int Cin, int Cout, int act) {
  const int n = blockIdx.x / Cout;
  const int co = blockIdx.x % Cout;
  const int t = threadIdx.x;
  const int x = t & 15, y = t >> 4;
  __shared__ float tile[16 * 256];
  const float* inb = in + n * Cin * 256;
  const float* wb = w + co * Cin * 9;
  float acc = bias[co];
  for (int c0 = 0; c0 < Cin; c0 += 16) {
    #pragma unroll
    for (int k = 0; k < 16; ++k) tile[k * 256 + t] = inb[(c0 + k) * 256 + t];
    __syncthreads();
    for (int k = 0; k < 16; ++k) {
      const float* wk = wb + (c0 + k) * 9;
      const float* tl = tile + k * 256;
      float a = wk[4] * tl[t];
      if (y > 0) {
        a += wk[1] * tl[t - 16];
        if (x > 0) a += wk[0] * tl[t - 17];
        if (x < 15) a += wk[2] * tl[t - 15];
      }
      if (x > 0) a += wk[3] * tl[t - 1];
      if (x < 15) a += wk[5] * tl[t + 1];
      if (y < 15) {
        a += wk[7] * tl[t + 16];
        if (x > 0) a += wk[6] * tl[t + 15];
        if (x < 15) a += wk[8] * tl[t + 17];
      }
      acc += a;
    }
    __syncthreads();
  }
  if (act == 1) acc = acc > 0.f ? acc : 0.01f * acc;
  else if (act == 2) acc = 1.f / (1.f + __expf(-acc));
  out[(n * Cout + co) * 256 + t] = acc;
}

// SE branch: global-avg-pool -> 1x1 conv (64->32) lrelu -> 1x1 conv (32->16) sigmoid.
__global__ __launch_bounds__(256) void k_se(
    const float* __restrict__ x, const float* __restrict__ w1, const float* __restrict__ b1,
    const float* __restrict__ w2, const float* __restrict__ b2, float* __restrict__ se) {
  const int n = blockIdx.x;
  const int t = threadIdx.x;
  __shared__ float pooled[64];
  __shared__ float h1[32];
  const int c = t >> 2, part = t & 3;
  const float* xp = x + (n * 64 + c) * 256 + part * 64;
  float s = 0.f;
  for (int k = 0; k < 64; ++k) s += xp[k];
  s += __shfl_xor(s, 1, 64);
  s += __shfl_xor(s, 2, 64);
  if (part == 0) pooled[c] = s * (1.f / 256.f);
  __syncthreads();
  if (t < 32) {
    float a = b1[t];
    for (int k = 0; k < 64; ++k) a += w1[t * 64 + k] * pooled[k];
    h1[t] = a > 0.f ? a : 0.01f * a;
  }
  __syncthreads();
  if (t < 16) {
    float a = b2[t];
    for (int k = 0; k < 32; ++k) a += w2[t * 32 + k] * h1[k];
    se[n * 16 + t] = 1.f / (1.f + __expf(-a));
  }
}

// ---------------------------------------------------------------------------
// Chronopoulos-Gear (fused single-reduction) Jacobi-PCG on the sparse normal
// equations: weighted graph Laplacian over 1024 nodes (4 fields x 256 pixels),
// anchored at the last pixel (SPD). One block of 256 threads (4 waves) per
// system; wave f owns field f; lane l owns pixels 4l..4l+3 (one row segment).
// 2 barriers / iteration; up/down/cross neighbor reads are float4 ds_read_b128.
// ---------------------------------------------------------------------------
__global__ __launch_bounds__(256) void k_pcg(
    const float* __restrict__ att, const float* __restrict__ grad,
    float* __restrict__ sol, int maxit, float tol2) {
  const int b = blockIdx.x;
  const int t = threadIdx.x;
  const int f = t >> 6;        // wave-uniform field id
  const int l = t & 63;        // lane
  const int row = l >> 2;      // pixel row owned by this lane
  const int c4 = l & 3;        // column block (cols 4*c4 .. 4*c4+3)
  const int i0 = 4 * l;        // first pixel of the lane's group

  __shared__ float ul[1024] __attribute__((aligned(16)));
  __shared__ float red[8] __attribute__((aligned(16)));
  float4* UL4 = reinterpret_cast<float4*>(ul);
  const float4* RED4 = reinterpret_cast<const float4*>(red);

  const int n = b >> 2, g = b & 3;
  const float* ab = att + (n * 40 + g * 10) * 256;
  const float* gb = grad + (n * 40 + g * 10) * 256;

  // per-field right/down equation ids
  int er, ed;
  if (f == 0)      { er = 4; ed = 9; }
  else if (f == 1) { er = 8; ed = 5; }
  else if (f == 2) { er = 2; ed = 7; }
  else             { er = 6; ed = 3; }

  float diag[4], invd[4], wLa[4], wRa[4], wUa[4], wDa[4], wXa[4], rr[4];
  #pragma unroll
  for (int k = 0; k < 4; ++k) {
    const int i = i0 + k;
    const int px = i & 15, py = i >> 4;
    float d = 1e-12f, rhs = 0.f;
    float wr = 0.f, wl = 0.f, wu = 0.f, wd = 0.f, wx = 0.f;
    if (px < 15) { float a = ab[er*256+i];    wr = a*a; d += wr; rhs += wr * gb[er*256+i]; }
    if (px > 0)  { float a = ab[er*256+i-1];  wl = a*a; d += wl; rhs -= wl * gb[er*256+i-1]; }
    if (py < 15) { float a = ab[ed*256+i];    wd = a*a; d += wd; rhs += wd * gb[ed*256+i]; }
    if (py > 0)  { float a = ab[ed*256+i-16]; wu = a*a; d += wu; rhs -= wu * gb[ed*256+i-16]; }
    // cross-field edges: e0: F2_i -- F0_{i+1}; e1: F3_i -- F1_{i+16}
    if (f == 0)      { if (px > 0)  { float a = ab[0*256+i-1];  wx = a*a; d += wx; rhs -= wx * gb[0*256+i-1]; } }
    else if (f == 1) { if (py > 0)  { float a = ab[1*256+i-16]; wx = a*a; d += wx; rhs -= wx * gb[1*256+i-16]; } }
    else if (f == 2) { if (px < 15) { float a = ab[0*256+i];    wx = a*a; d += wx; rhs += wx * gb[0*256+i]; } }
    else             { if (py < 15) { float a = ab[1*256+i];    wx = a*a; d += wx; rhs += wx * gb[1*256+i]; } }
    if (i == 255) {  // anchor rows at the last pixel
      if (f == 0) {
        float a4 = ab[4*256+255], a9 = ab[9*256+255];
        d += a4*a4 + a9*a9; rhs += a4*a4*gb[4*256+255] + a9*a9*gb[9*256+255];
      } else if (f == 1) {
        float a5 = ab[5*256+255], a8 = ab[8*256+255];
        d += a5*a5 + a8*a8; rhs += a5*a5*gb[5*256+255] + a8*a8*gb[8*256+255];
      } else if (f == 2) {
        float a0 = ab[0*256+255], a2 = ab[2*256+255], a7 = ab[7*256+255];
        d += a0*a0 + a2*a2 + a7*a7;
        rhs += a0*a0*gb[0*256+255] + a2*a2*gb[2*256+255] + a7*a7*gb[7*256+255];
      } else {
        float a1 = ab[1*256+255], a3 = ab[3*256+255], a6 = ab[6*256+255];
        d += a1*a1 + a3*a3 + a6*a6;
        rhs += a1*a1*gb[1*256+255] + a3*a3*gb[3*256+255] + a6*a6*gb[6*256+255];
      }
    }
    diag[k] = d; invd[k] = 1.f / d;
    wRa[k] = wr; wLa[k] = wl; wUa[k] = wu; wDa[k] = wd; wXa[k] = wx;
    rr[k] = rhs;
  }

  // LDS addresses (clamped in-bounds; clamped neighbors have weight 0).
  const int base4 = f * 64 + l;                       // own float4 slot
  const int upIdx = (row > 0)  ? base4 - 4 : base4;
  const int dnIdx = (row < 15) ? base4 + 4 : base4;
  int cIdx, xAddr = 0;
  if (f == 0)      { cIdx = 128 + l;                        xAddr = (c4 > 0) ? 512 + i0 - 1 : 512; }
  else if (f == 1) { cIdx = (row > 0) ? 192 + l - 4 : 192 + l; }
  else if (f == 2) { cIdx = l;                              xAddr = (c4 < 3) ? i0 + 4 : 0; }
  else             { cIdx = (row < 15) ? 64 + l + 4 : 64 + l; }
  const int leftAddr  = (c4 > 0) ? f * 256 + i0 - 1 : f * 256;
  const int rightAddr = (c4 < 3) ? f * 256 + i0 + 4 : f * 256;

  float xx[4], uu[4], ww[4], pp[4], ss[4];
  #pragma unroll
  for (int k = 0; k < 4; ++k) { xx[k] = 0.f; pp[k] = 0.f; ss[k] = 0.f; uu[k] = invd[k] * rr[k]; }

  // SpMV: ww = A uu (uu mirrored in ul).
  auto spmv = [&]() {
    float4 up4 = UL4[upIdx];
    float4 dn4 = UL4[dnIdx];
    float4 cr4 = UL4[cIdx];
    float uLs = ul[leftAddr];
    float uRs = ul[rightAddr];
    float xs = 0.f;
    if (f == 0 || f == 2) xs = ul[xAddr];
    float up_[4] = {up4.x, up4.y, up4.z, up4.w};
    float dn_[4] = {dn4.x, dn4.y, dn4.z, dn4.w};
    float cr_[4] = {cr4.x, cr4.y, cr4.z, cr4.w};
    float xv[4];
    if (f == 0)      { xv[0] = xs;     xv[1] = cr_[0]; xv[2] = cr_[1]; xv[3] = cr_[2]; }
    else if (f == 2) { xv[0] = cr_[1]; xv[1] = cr_[2]; xv[2] = cr_[3]; xv[3] = xs; }
    else             { xv[0] = cr_[0]; xv[1] = cr_[1]; xv[2] = cr_[2]; xv[3] = cr_[3]; }
    float uLv[4] = {uLs, uu[0], uu[1], uu[2]};
    float uRv[4] = {uu[1], uu[2], uu[3], uRs};
    #pragma unroll
    for (int k = 0; k < 4; ++k) {
      ww[k] = diag[k] * uu[k] - wLa[k] * uLv[k] - wRa[k] * uRv[k]
            - wUa[k] * up_[k] - wDa[k] * dn_[k] - wXa[k] * xv[k];
    }
  };

  // reduce gp,dp over the block -> gamma,delta (1 barrier)
  float gamma, delta;
  auto reduce2 = [&](float gp, float dp) {
    #pragma unroll
    for (int o = 1; o <= 32; o <<= 1) {
      gp += __shfl_xor(gp, o, 64);
      dp += __shfl_xor(dp, o, 64);
    }
    if (l == 0) { red[2 * f] = gp; red[2 * f + 1] = dp; }
    __syncthreads();
    float4 ra = RED4[0], rb = RED4[1];
    gamma = ra.x + ra.z + rb.x + rb.z;
    delta = ra.y + ra.w + rb.y + rb.w;
  };

  // init: u0 = D^-1 r0, w0 = A u0, gamma0 = r.u, delta0 = w.u
  UL4[base4] = make_float4(uu[0], uu[1], uu[2], uu[3]);
  __syncthreads();
  spmv();
  {
    float gp = 0.f, dp = 0.f;
    #pragma unroll
    for (int k = 0; k < 4; ++k) { gp += rr[k] * uu[k]; dp += ww[k] * uu[k]; }
    reduce2(gp, dp);
  }
  const float thresh = tol2 * gamma;
  float gamma_old = gamma, alpha_old = 1.f;

  for (int it = 0; it < maxit && gamma > thresh; ++it) {
    float beta, alpha;
    if (it == 0) { beta = 0.f; alpha = gamma / delta; }
    else {
      beta = gamma / gamma_old;
      alpha = gamma / (delta - beta * gamma / alpha_old);
    }
    #pragma unroll
    for (int k = 0; k < 4; ++k) {
      pp[k] = uu[k] + beta * pp[k];
      ss[k] = ww[k] + beta * ss[k];
      xx[k] += alpha * pp[k];
      rr[k] -= alpha * ss[k];
      uu[k] = invd[k] * rr[k];
    }
    UL4[base4] = make_float4(uu[0], uu[1], uu[2], uu[3]);
    __syncthreads();
    spmv();
    float gp = 0.f, dp = 0.f;
    #pragma unroll
    for (int k = 0; k < 4; ++k) { gp += rr[k] * uu[k]; dp += ww[k] * uu[k]; }
    gamma_old = gamma; alpha_old = alpha;
    reduce2(gp, dp);
  }

  reinterpret_cast<float4*>(sol)[b * 256 + base4] = make_float4(xx[0], xx[1], xx[2], xx[3]);
}

// GroupNorm(1, 16) per sample + gn affine + SE scale.
__global__ __launch_bounds__(1024) void k_norm(
    const float* __restrict__ sol, const float* __restrict__ se,
    const float* __restrict__ gn_w, const float* __restrict__ gn_b,
    float* __restrict__ out) {
  const int n = blockIdx.x;
  const int t = threadIdx.x;
  __shared__ float redl[17];
  float v[4];
  float s = 0.f, s2 = 0.f;
  #pragma unroll
  for (int k = 0; k < 4; ++k) {
    int idx = t + k * 1024;
    int c = idx >> 8, pix = idx & 255;
    int g = c >> 2, ff = c & 3;
    float val = sol[(n * 4 + g) * 1024 + ff * 256 + pix];
    v[k] = val; s += val; s2 += val * val;
  }
  // block reduce (16 waves)
  #pragma unroll
  for (int o = 32; o >= 1; o >>= 1) { s += __shfl_xor(s, o, 64); s2 += __shfl_xor(s2, o, 64); }
  const int wid = t >> 6, lane = t & 63;
  __shared__ float rs[16], rs2[16];
  if (lane == 0) { rs[wid] = s; rs2[wid] = s2; }
  __syncthreads();
  s = 0.f; s2 = 0.f;
  #pragma unroll
  for (int k = 0; k < 16; ++k) { s += rs[k]; s2 += rs2[k]; }
  float mu = s * (1.f / 4096.f);
  float var = s2 * (1.f / 4096.f) - mu * mu;
  float rstd = rsqrtf(var + 1e-5f);
  (void)redl;
  #pragma unroll
  for (int k = 0; k < 4; ++k) {
    int idx = t + k * 1024;
    int c = idx >> 8;
    float yv = (v[k] - mu) * rstd * gn_w[c] + gn_b[c];
    yv *= se[n * 16 + c];
    out[n * 4096 + idx] = yv;
  }
}

extern "C" void kernel_launch(void* const* d_in, const int* in_sizes, int n_in,
                              void* d_out, int out_size, void* d_ws, size_t ws_size,
                              hipStream_t stream) {
  const float* x       = (const float*)d_in[0];
  const float* grad_w1 = (const float*)d_in[1];
  const float* grad_b1 = (const float*)d_in[2];
  const float* grad_w2 = (const float*)d_in[3];
  const float* grad_b2 = (const float*)d_in[4];
  const float* att_w1  = (const float*)d_in[5];
  const float* att_b1  = (const float*)d_in[6];
  const float* att_w2  = (const float*)d_in[7];
  const float* att_b2  = (const float*)d_in[8];
  const float* se_w1   = (const float*)d_in[9];
  const float* se_b1   = (const float*)d_in[10];
  const float* se_w2   = (const float*)d_in[11];
  const float* se_b2   = (const float*)d_in[12];
  const float* gn_w    = (const float*)d_in[13];
  const float* gn_b    = (const float*)d_in[14];
  const float* post_w  = (const float*)d_in[15];
  const float* post_b  = (const float*)d_in[16];
  float* out = (float*)d_out;
  float* ws = (float*)d_ws;

  // Workspace layout (floats). sol/ynorm reuse t1 after conv2 completes.
  float* t1    = ws;                // 65536 (grad-branch conv1 out)
  float* t2    = ws + 65536;        // 65536 (att-branch conv1 out)
  float* gradb = ws + 131072;       // 40960
  float* attb  = ws + 172032;       // 40960
  float* seb   = ws + 212992;       // 64
  float* solb  = ws;                // 16384 (reuses t1)
  float* ynorm = ws + 16384;        // 16384 (reuses t1)

  k_conv3x3_dual<<<2 * 4 * 64, 256, 0, stream>>>(
      x, x, grad_w1, grad_b1, att_w1, att_b1, t1, t2, 64, 64, 1, 1);
  k_conv3x3_dual<<<2 * 4 * 40, 256, 0, stream>>>(
      t1, t2, grad_w2, grad_b2, att_w2, att_b2, gradb, attb, 64, 40, 0, 2);
  k_se<<<4, 256, 0, stream>>>(x, se_w1, se_b1, se_w2, se_b2, seb);
  k_pcg<<<16, 256, 0, stream>>>(attb, gradb, solb, 3000, 1e-10f);
  k_norm<<<4, 1024, 0, stream>>>(solb, seb, gn_w, gn_b, ynorm);
  k_conv3x3<<<4 * 128, 256, 0, stream>>>(ynorm, post_w, post_b, out, 16, 128, 0);
}

// Round 3
// 111.214 us; speedup vs baseline: 2.8976x; 1.6602x over previous
//
#include <hip/hip_runtime.h>

#define NCHEB 8

// ---------------------------------------------------------------------------
// Dual-branch direct 3x3 SAME conv on 16x16 images (grad + att branches in one
// dispatch). One (branch, n, c_out) plane per 256-thread block.
// act: 0=none, 1=leaky_relu(0.01), 2=sigmoid
// ---------------------------------------------------------------------------
__global__ __launch_bounds__(256) void k_conv3x3_dual(
    const float* __restrict__ in_a, const float* __restrict__ in_b,
    const float* __restrict__ w_a, const float* __restrict__ bias_a,
    const float* __restrict__ w_b, const float* __restrict__ bias_b,
    float* __restrict__ out_a, float* __restrict__ out_b,
    int Cin, int Cout, int act_a, int act_b) {
  int nc = blockIdx.x;
  const int half = gridDim.x >> 1;
  const int br = nc >= half ? 1 : 0;
  if (br) nc -= half;
  const float* in = br ? in_b : in_a;
  const float* w = br ? w_b : w_a;
  const float* bias = br ? bias_b : bias_a;
  float* out = br ? out_b : out_a;
  const int act = br ? act_b : act_a;

  const int n = nc / Cout;
  const int co = nc % Cout;
  const int t = threadIdx.x;
  const int x = t & 15, y = t >> 4;
  __shared__ float tile[16 * 256];
  const float* inb = in + n * Cin * 256;
  const float* wb = w + co * Cin * 9;
  float acc = bias[co];
  for (int c0 = 0; c0 < Cin; c0 += 16) {
    #pragma unroll
    for (int k = 0; k < 16; ++k) tile[k * 256 + t] = inb[(c0 + k) * 256 + t];
    __syncthreads();
    for (int k = 0; k < 16; ++k) {
      const float* wk = wb + (c0 + k) * 9;
      const float* tl = tile + k * 256;
      float a = wk[4] * tl[t];
      if (y > 0) {
        a += wk[1] * tl[t - 16];
        if (x > 0) a += wk[0] * tl[t - 17];
        if (x < 15) a += wk[2] * tl[t - 15];
      }
      if (x > 0) a += wk[3] * tl[t - 1];
      if (x < 15) a += wk[5] * tl[t + 1];
      if (y < 15) {
        a += wk[7] * tl[t + 16];
        if (x > 0) a += wk[6] * tl[t + 15];
        if (x < 15) a += wk[8] * tl[t + 17];
      }
      acc += a;
    }
    __syncthreads();
  }
  if (act == 1) acc = acc > 0.f ? acc : 0.01f * acc;
  else if (act == 2) acc = 1.f / (1.f + __expf(-acc));
  out[(n * Cout + co) * 256 + t] = acc;
}

// Single-branch conv (post conv).
__global__ __launch_bounds__(256) void k_conv3x3(
    const float* __restrict__ in, const float* __restrict__ w,
    const float* __restrict__ bias, float* __restrict__ out,
    int Cin, int Cout, int act) {
  const int n = blockIdx.x / Cout;
  const int co = blockIdx.x % Cout;
  const int t = threadIdx.x;
  const int x = t & 15, y = t >> 4;
  __shared__ float tile[16 * 256];
  const float* inb = in + n * Cin * 256;
  const float* wb = w + co * Cin * 9;
  float acc = bias[co];
  for (int c0 = 0; c0 < Cin; c0 += 16) {
    #pragma unroll
    for (int k = 0; k < 16; ++k) tile[k * 256 + t] = inb[(c0 + k) * 256 + t];
    __syncthreads();
    for (int k = 0; k < 16; ++k) {
      const float* wk = wb + (c0 + k) * 9;
      const float* tl = tile + k * 256;
      float a = wk[4] * tl[t];
      if (y > 0) {
        a += wk[1] * tl[t - 16];
        if (x > 0) a += wk[0] * tl[t - 17];
        if (x < 15) a += wk[2] * tl[t - 15];
      }
      if (x > 0) a += wk[3] * tl[t - 1];
      if (x < 15) a += wk[5] * tl[t + 1];
      if (y < 15) {
        a += wk[7] * tl[t + 16];
        if (x > 0) a += wk[6] * tl[t + 15];
        if (x < 15) a += wk[8] * tl[t + 17];
      }
      acc += a;
    }
    __syncthreads();
  }
  if (act == 1) acc = acc > 0.f ? acc : 0.01f * acc;
  else if (act == 2) acc = 1.f / (1.f + __expf(-acc));
  out[(n * Cout + co) * 256 + t] = acc;
}

// SE branch: global-avg-pool -> 1x1 conv (64->32) lrelu -> 1x1 conv (32->16) sigmoid.
__global__ __launch_bounds__(256) void k_se(
    const float* __restrict__ x, const float* __restrict__ w1, const float* __restrict__ b1,
    const float* __restrict__ w2, const float* __restrict__ b2, float* __restrict__ se) {
  const int n = blockIdx.x;
  const int t = threadIdx.x;
  __shared__ float pooled[64];
  __shared__ float h1[32];
  const int c = t >> 2, part = t & 3;
  const float* xp = x + (n * 64 + c) * 256 + part * 64;
  float s = 0.f;
  for (int k = 0; k < 64; ++k) s += xp[k];
  s += __shfl_xor(s, 1, 64);
  s += __shfl_xor(s, 2, 64);
  if (part == 0) pooled[c] = s * (1.f / 256.f);
  __syncthreads();
  if (t < 32) {
    float a = b1[t];
    for (int k = 0; k < 64; ++k) a += w1[t * 64 + k] * pooled[k];
    h1[t] = a > 0.f ? a : 0.01f * a;
  }
  __syncthreads();
  if (t < 16) {
    float a = b2[t];
    for (int k = 0; k < 32; ++k) a += w2[t * 32 + k] * h1[k];
    se[n * 16 + t] = 1.f / (1.f + __expf(-a));
  }
}

// ---------------------------------------------------------------------------
// Wave-local Chebyshev(NCHEB)-preconditioned CG (Chronopoulos-Gear fused form).
// The 1024-node graph splits into two independent 512-node SPD components:
//   comp 0: fields {F0,F2} coupled by eqn-0 cross edges (x-direction)
//   comp 1: fields {F1,F3} coupled by eqn-1 cross edges (y-direction)
// One 64-lane wave per (system, component); lane l owns pixels 4l..4l+3 of
// BOTH fields. No __syncthreads anywhere: neighbor exchange via wave-private
// ping-pong LDS (in-order LDS pipe), reductions via __shfl_xor butterfly.
// One reduction per NCHEB SpMVs; Chebyshev scalars constant-fold.
// ---------------------------------------------------------------------------
__global__ __launch_bounds__(64) void k_pcg(
    const float* __restrict__ att, const float* __restrict__ grad,
    float* __restrict__ sol, int maxit, float tol2) {
  const int sys = blockIdx.x >> 1;
  const int wv = blockIdx.x & 1;
  const int l = threadIdx.x;
  const int row = l >> 2, c4 = l & 3;
  const int i0 = 4 * l;

  __shared__ float lds[1024] __attribute__((aligned(16)));
  float4* LDS4 = reinterpret_cast<float4*>(lds);

  const int n = sys >> 2, g = sys & 3;
  const float* ab = att + (n * 40 + g * 10) * 256;
  const float* gb = grad + (n * 40 + g * 10) * 256;

  int era, eda, erb, edb, ec, fa, fb;
  if (wv == 0) { fa = 0; fb = 2; era = 4; eda = 9; erb = 2; edb = 7; ec = 0; }
  else         { fa = 1; fb = 3; era = 8; eda = 5; erb = 6; edb = 3; ec = 1; }

  auto L4 = [](const float* p) { return *reinterpret_cast<const float4*>(p); };
  auto unp = [](float4 v, float* o) { o[0] = v.x; o[1] = v.y; o[2] = v.z; o[3] = v.w; };

  float wLa[4], wRa[4], wUa[4], wDa[4], wXa[4], dga[4], iva[4], rsa[4];
  float wLb[4], wRb[4], wUb[4], wDb[4], wXb[4], dgb[4], ivb[4], rsb[4];

  // --- field a (fa) weights & rhs ---
  float rA[4], gA[4], dA[4], hA[4], uA[4] = {0,0,0,0}, vA[4] = {0,0,0,0};
  unp(L4(ab + era * 256 + i0), rA); unp(L4(gb + era * 256 + i0), gA);
  unp(L4(ab + eda * 256 + i0), dA); unp(L4(gb + eda * 256 + i0), hA);
  if (row > 0) { unp(L4(ab + eda * 256 + i0 - 16), uA); unp(L4(gb + eda * 256 + i0 - 16), vA); }
  float rlA = (l > 0) ? ab[era * 256 + i0 - 1] : 0.f;
  float glA = (l > 0) ? gb[era * 256 + i0 - 1] : 0.f;
  // cross data
  float cX[4], gX[4], cU[4] = {0,0,0,0}, gU[4] = {0,0,0,0};
  unp(L4(ab + ec * 256 + i0), cX); unp(L4(gb + ec * 256 + i0), gX);
  float clX = 0.f, glX = 0.f;
  if (wv == 0) { if (l > 0) { clX = ab[ec * 256 + i0 - 1]; glX = gb[ec * 256 + i0 - 1]; } }
  else if (row > 0) { unp(L4(ab + ec * 256 + i0 - 16), cU); unp(L4(gb + ec * 256 + i0 - 16), gU); }

  #pragma unroll
  for (int k = 0; k < 4; ++k) {
    wRa[k] = (k < 3 || c4 < 3) ? rA[k] * rA[k] : 0.f;
    wLa[k] = (k > 0) ? rA[k-1] * rA[k-1] : ((c4 > 0) ? rlA * rlA : 0.f);
    wDa[k] = (row < 15) ? dA[k] * dA[k] : 0.f;
    wUa[k] = (row > 0) ? uA[k] * uA[k] : 0.f;
    float rhs = wRa[k] * gA[k] - wLa[k] * ((k > 0) ? gA[k-1] : glA)
              + wDa[k] * hA[k] - wUa[k] * vA[k];
    float wx, gx;
    if (wv == 0) {
      wx = (k > 0) ? cX[k-1] * cX[k-1] : ((c4 > 0) ? clX * clX : 0.f);
      gx = (k > 0) ? gX[k-1] : glX;
    } else {
      wx = (row > 0) ? cU[k] * cU[k] : 0.f;
      gx = gU[k];
    }
    wXa[k] = wx;
    rhs -= wx * gx;           // field a holds the "-1" entry of the cross eqn
    rsa[k] = rhs;
    dga[k] = 1e-12f + wRa[k] + wLa[k] + wDa[k] + wUa[k] + wx;
  }

  // --- field b (fb) weights & rhs ---
  float rB[4], gB[4], dB[4], hB[4], uB[4] = {0,0,0,0}, vB[4] = {0,0,0,0};
  unp(L4(ab + erb * 256 + i0), rB); unp(L4(gb + erb * 256 + i0), gB);
  unp(L4(ab + edb * 256 + i0), dB); unp(L4(gb + edb * 256 + i0), hB);
  if (row > 0) { unp(L4(ab + edb * 256 + i0 - 16), uB); unp(L4(gb + edb * 256 + i0 - 16), vB); }
  float rlB = (l > 0) ? ab[erb * 256 + i0 - 1] : 0.f;
  float glB = (l > 0) ? gb[erb * 256 + i0 - 1] : 0.f;

  #pragma unroll
  for (int k = 0; k < 4; ++k) {
    wRb[k] = (k < 3 || c4 < 3) ? rB[k] * rB[k] : 0.f;
    wLb[k] = (k > 0) ? rB[k-1] * rB[k-1] : ((c4 > 0) ? rlB * rlB : 0.f);
    wDb[k] = (row < 15) ? dB[k] * dB[k] : 0.f;
    wUb[k] = (row > 0) ? uB[k] * uB[k] : 0.f;
    float wx;
    if (wv == 0) wx = (k < 3 || c4 < 3) ? cX[k] * cX[k] : 0.f;
    else         wx = (row < 15) ? cX[k] * cX[k] : 0.f;
    wXb[k] = wx;
    rsb[k] = wRb[k] * gB[k] - wLb[k] * ((k > 0) ? gB[k-1] : glB)
           + wDb[k] * hB[k] - wUb[k] * vB[k]
           + wx * gX[k];      // field b holds the "+1" entry of the cross eqn
    dgb[k] = 1e-12f + wRb[k] + wLb[k] + wDb[k] + wUb[k] + wx;
  }

  // --- anchors at pixel 255 (lane 63, k=3); all entries are +1 ---
  if (l == 63) {
    float wr = rA[3] * rA[3], wd = dA[3] * dA[3];
    dga[3] += wr + wd;
    rsa[3] += wr * gA[3] + wd * hA[3];
    float wc = cX[3] * cX[3], wrb = rB[3] * rB[3], wdb = dB[3] * dB[3];
    dgb[3] += wc + wrb + wdb;
    rsb[3] += wc * gX[3] + wrb * gB[3] + wdb * hB[3];
  }
  #pragma unroll
  for (int k = 0; k < 4; ++k) { iva[k] = 1.f / dga[k]; ivb[k] = 1.f / dgb[k]; }

  // --- LDS neighbor slots (clamped; clamped neighbors have weight 0) ---
  const int upS = (row > 0) ? l - 4 : l;
  const int dnS = (row < 15) ? l + 4 : l;
  const int lF = (l > 0) ? 4 * l - 1 : 0;
  const int rF = (l < 63) ? 4 * l + 4 : 0;

  int pp = 0;
  float ua[4], ub[4], wa[4], wb[4];

  auto spmv = [&](const float (&ia_)[4], const float (&ib_)[4],
                  float (&oa)[4], float (&ob)[4]) {
    const int B = pp << 7;   // float4 slot base
    const int fB = pp << 9;  // float base
    LDS4[B + l]      = make_float4(ia_[0], ia_[1], ia_[2], ia_[3]);
    LDS4[B + 64 + l] = make_float4(ib_[0], ib_[1], ib_[2], ib_[3]);
    float aU[4], aD[4], bU[4], bD[4];
    unp(LDS4[B + upS], aU);      unp(LDS4[B + dnS], aD);
    unp(LDS4[B + 64 + upS], bU); unp(LDS4[B + 64 + dnS], bD);
    float aL = lds[fB + lF], aR = lds[fB + rF];
    float bL = lds[fB + 256 + lF], bR = lds[fB + 256 + rF];
    float uaL[4] = {aL, ia_[0], ia_[1], ia_[2]};
    float uaR[4] = {ia_[1], ia_[2], ia_[3], aR};
    float ubL[4] = {bL, ib_[0], ib_[1], ib_[2]};
    float ubR[4] = {ib_[1], ib_[2], ib_[3], bR};
    #pragma unroll
    for (int k = 0; k < 4; ++k) {
      float cA = (wv == 0) ? ubL[k] : bU[k];
      float cB = (wv == 0) ? uaR[k] : aD[k];
      oa[k] = dga[k] * ia_[k] - wLa[k] * uaL[k] - wRa[k] * uaR[k]
            - wUa[k] * aU[k] - wDa[k] * aD[k] - wXa[k] * cA;
      ob[k] = dgb[k] * ib_[k] - wLb[k] * ubL[k] - wRb[k] * ubR[k]
            - wUb[k] * bU[k] - wDb[k] * bD[k] - wXb[k] * cB;
    }
    pp ^= 1;
  };

  constexpr float lo = 0.04f, hi = 2.0f;
  constexpr float th = (hi + lo) * 0.5f, dl = (hi - lo) * 0.5f, s1 = th / dl;

  float xa[4] = {0,0,0,0}, xb[4] = {0,0,0,0};
  float ra_[4], rb_[4], pa[4] = {0,0,0,0}, pb[4] = {0,0,0,0};
  float sa[4] = {0,0,0,0}, sb[4] = {0,0,0,0};
  #pragma unroll
  for (int k = 0; k < 4; ++k) { ra_[k] = rsa[k]; rb_[k] = rsb[k]; }

  // Chebyshev(NCHEB) on D^-1 A over [lo,hi]: u = M^-1 r, w = A u (accumulated).
  auto cheb = [&]() {
    float da_[4], db_[4], ta[4], tb[4], qa[4], qb[4];
    #pragma unroll
    for (int k = 0; k < 4; ++k) {
      da_[k] = (1.0f / th) * iva[k] * ra_[k];
      db_[k] = (1.0f / th) * ivb[k] * rb_[k];
      ua[k] = da_[k]; ub[k] = db_[k];
    }
    spmv(da_, db_, ta, tb);
    #pragma unroll
    for (int k = 0; k < 4; ++k) {
      wa[k] = ta[k]; wb[k] = tb[k];
      qa[k] = ra_[k] - ta[k]; qb[k] = rb_[k] - tb[k];
    }
    float rho = 1.0f / s1;
    #pragma unroll
    for (int j = 1; j < NCHEB; ++j) {
      float rho2 = 1.0f / (2.0f * s1 - rho);
      float c1 = rho2 * rho, c2 = 2.0f * rho2 / dl;
      #pragma unroll
      for (int k = 0; k < 4; ++k) {
        da_[k] = c1 * da_[k] + c2 * iva[k] * qa[k];
        db_[k] = c1 * db_[k] + c2 * ivb[k] * qb[k];
        ua[k] += da_[k]; ub[k] += db_[k];
      }
      spmv(da_, db_, ta, tb);
      #pragma unroll
      for (int k = 0; k < 4; ++k) {
        wa[k] += ta[k]; wb[k] += tb[k];
        qa[k] -= ta[k]; qb[k] -= tb[k];
      }
      rho = rho2;
    }
  };

  float gamma, delta;
  auto dots = [&]() {
    float gp = 0.f, dp = 0.f;
    #pragma unroll
    for (int k = 0; k < 4; ++k) {
      gp += ra_[k] * ua[k] + rb_[k] * ub[k];
      dp += wa[k] * ua[k] + wb[k] * ub[k];
    }
    #pragma unroll
    for (int o = 1; o <= 32; o <<= 1) {
      gp += __shfl_xor(gp, o, 64);
      dp += __shfl_xor(dp, o, 64);
    }
    gamma = gp; delta = dp;
  };

  cheb();
  dots();
  const float thresh = tol2 * gamma;
  float gamma_old = gamma, alpha_old = 1.f;

  for (int it = 0; it < maxit && gamma > thresh; ++it) {
    float beta = (it == 0) ? 0.f : gamma / gamma_old;
    float alpha = (it == 0) ? gamma / delta
                            : gamma / (delta - beta * gamma / alpha_old);
    #pragma unroll
    for (int k = 0; k < 4; ++k) {
      pa[k] = ua[k] + beta * pa[k];  pb[k] = ub[k] + beta * pb[k];
      sa[k] = wa[k] + beta * sa[k];  sb[k] = wb[k] + beta * sb[k];
      xa[k] += alpha * pa[k];        xb[k] += alpha * pb[k];
      ra_[k] -= alpha * sa[k];       rb_[k] -= alpha * sb[k];
    }
    gamma_old = gamma; alpha_old = alpha;
    cheb();
    dots();
  }

  float4* sol4 = reinterpret_cast<float4*>(sol);
  sol4[sys * 256 + fa * 64 + l] = make_float4(xa[0], xa[1], xa[2], xa[3]);
  sol4[sys * 256 + fb * 64 + l] = make_float4(xb[0], xb[1], xb[2], xb[3]);
}

// GroupNorm(1, 16) per sample + gn affine + SE scale.
__global__ __launch_bounds__(1024) void k_norm(
    const float* __restrict__ sol, const float* __restrict__ se,
    const float* __restrict__ gn_w, const float* __restrict__ gn_b,
    float* __restrict__ out) {
  const int n = blockIdx.x;
  const int t = threadIdx.x;
  float v[4];
  float s = 0.f, s2 = 0.f;
  #pragma unroll
  for (int k = 0; k < 4; ++k) {
    int idx = t + k * 1024;
    int c = idx >> 8, pix = idx & 255;
    int g = c >> 2, ff = c & 3;
    float val = sol[(n * 4 + g) * 1024 + ff * 256 + pix];
    v[k] = val; s += val; s2 += val * val;
  }
  #pragma unroll
  for (int o = 32; o >= 1; o >>= 1) { s += __shfl_xor(s, o, 64); s2 += __shfl_xor(s2, o, 64); }
  const int wid = t >> 6, lane = t & 63;
  __shared__ float rs[16], rs2[16];
  if (lane == 0) { rs[wid] = s; rs2[wid] = s2; }
  __syncthreads();
  s = 0.f; s2 = 0.f;
  #pragma unroll
  for (int k = 0; k < 16; ++k) { s += rs[k]; s2 += rs2[k]; }
  float mu = s * (1.f / 4096.f);
  float var = s2 * (1.f / 4096.f) - mu * mu;
  float rstd = rsqrtf(var + 1e-5f);
  #pragma unroll
  for (int k = 0; k < 4; ++k) {
    int idx = t + k * 1024;
    int c = idx >> 8;
    float yv = (v[k] - mu) * rstd * gn_w[c] + gn_b[c];
    yv *= se[n * 16 + c];
    out[n * 4096 + idx] = yv;
  }
}

extern "C" void kernel_launch(void* const* d_in, const int* in_sizes, int n_in,
                              void* d_out, int out_size, void* d_ws, size_t ws_size,
                              hipStream_t stream) {
  const float* x       = (const float*)d_in[0];
  const float* grad_w1 = (const float*)d_in[1];
  const float* grad_b1 = (const float*)d_in[2];
  const float* grad_w2 = (const float*)d_in[3];
  const float* grad_b2 = (const float*)d_in[4];
  const float* att_w1  = (const float*)d_in[5];
  const float* att_b1  = (const float*)d_in[6];
  const float* att_w2  = (const float*)d_in[7];
  const float* att_b2  = (const float*)d_in[8];
  const float* se_w1   = (const float*)d_in[9];
  const float* se_b1   = (const float*)d_in[10];
  const float* se_w2   = (const float*)d_in[11];
  const float* se_b2   = (const float*)d_in[12];
  const float* gn_w    = (const float*)d_in[13];
  const float* gn_b    = (const float*)d_in[14];
  const float* post_w  = (const float*)d_in[15];
  const float* post_b  = (const float*)d_in[16];
  float* out = (float*)d_out;
  float* ws = (float*)d_ws;

  float* t1    = ws;                // 65536 (grad-branch conv1 out)
  float* t2    = ws + 65536;        // 65536 (att-branch conv1 out)
  float* gradb = ws + 131072;       // 40960
  float* attb  = ws + 172032;       // 40960
  float* seb   = ws + 212992;       // 64
  float* solb  = ws;                // 16384 (reuses t1)
  float* ynorm = ws + 16384;        // 16384 (reuses t1)

  k_conv3x3_dual<<<2 * 4 * 64, 256, 0, stream>>>(
      x, x, grad_w1, grad_b1, att_w1, att_b1, t1, t2, 64, 64, 1, 1);
  k_conv3x3_dual<<<2 * 4 * 40, 256, 0, stream>>>(
      t1, t2, grad_w2, grad_b2, att_w2, att_b2, gradb, attb, 64, 40, 0, 2);
  k_se<<<4, 256, 0, stream>>>(x, se_w1, se_b1, se_w2, se_b2, seb);
  k_pcg<<<32, 64, 0, stream>>>(attb, gradb, solb, 300, 1e-10f);
  k_norm<<<4, 1024, 0, stream>>>(solb, seb, gn_w, gn_b, ynorm);
  k_conv3x3<<<4 * 128, 256, 0, stream>>>(ynorm, post_w, post_b, out, 16, 128, 0);
}

// Round 4
// 84.186 us; speedup vs baseline: 3.8279x; 1.3211x over previous
//
#include <hip/hip_runtime.h>

#define NCHEB 8

typedef __attribute__((ext_vector_type(8))) short vs8;
typedef __attribute__((ext_vector_type(4))) float vf4;
typedef __attribute__((ext_vector_type(16))) float vf16;

__device__ __forceinline__ unsigned short f2bf(float f) {
  union { float f; unsigned int u; } x; x.f = f;
  unsigned int r = (x.u + 0x7FFFu + ((x.u >> 16) & 1u)) >> 16;
  return (unsigned short)r;
}

// ---------------------------------------------------------------------------
// MFMA 3x3 SAME conv on 16x16 images as 9 shifted GEMMs (bf16 in, f32 acc).
// Block = (branch, image): 4 waves; wave owns 64 pixels (4 M-tiles of 16).
// X in LDS pixel-major [pix][ci] with XOR chunk swizzle (conflict-free b128);
// W in LDS [e][co][ci] transposed bf16, same swizzle keyed on co.
// SE==true: blocks 8..11 run the squeeze-excite branch instead.
// ---------------------------------------------------------------------------
template<int COUT, int COP, int NT, bool SE>
__global__ __launch_bounds__(256) void k_conv(
    const float* __restrict__ inA, const float* __restrict__ inB,
    const float* __restrict__ wA, const float* __restrict__ bA,
    const float* __restrict__ wB, const float* __restrict__ bB,
    float* __restrict__ outA, float* __restrict__ outB,
    int actA, int actB,
    const float* __restrict__ x,
    const float* __restrict__ sw1, const float* __restrict__ sb1,
    const float* __restrict__ sw2, const float* __restrict__ sb2,
    float* __restrict__ seo) {
  __shared__ unsigned short Xl[256 * 64];        // 32 KB
  __shared__ unsigned short Wl[9 * COP * 64];    // 72/54 KB
  __shared__ float sp[64];
  __shared__ float sh1[32];
  const int b = blockIdx.x;
  const int t = threadIdx.x;

  if (SE && b >= 8) {  // ---- squeeze-excite branch (4 blocks) ----
    const int n = b - 8;
    const int c = t >> 2, part = t & 3;
    const float* xp = x + (n * 64 + c) * 256 + part * 64;
    float s = 0.f;
    for (int k = 0; k < 64; ++k) s += xp[k];
    s += __shfl_xor(s, 1, 64);
    s += __shfl_xor(s, 2, 64);
    if (part == 0) sp[c] = s * (1.f / 256.f);
    __syncthreads();
    if (t < 32) {
      float a = sb1[t];
      for (int k = 0; k < 64; ++k) a += sw1[t * 64 + k] * sp[k];
      sh1[t] = a > 0.f ? a : 0.01f * a;
    }
    __syncthreads();
    if (t < 16) {
      float a = sb2[t];
      for (int k = 0; k < 32; ++k) a += sw2[t * 32 + k] * sh1[k];
      seo[n * 16 + t] = 1.f / (1.f + __expf(-a));
    }
    return;
  }

  const int br = b >> 2, n = b & 3;
  const float* inp = (br ? inB : inA) + n * 64 * 256;
  const float* wsrc = br ? wB : wA;
  const float* bias = br ? bB : bA;
  float* outp = (br ? outB : outA) + n * COUT * 256;
  const int act = br ? actB : actA;

  // ---- stage X: [pix][ci] bf16, chunk c' = chunk ^ (pix&7) ----
  {
    const int p = t;
    #pragma unroll
    for (int q = 0; q < 8; ++q) {
      vs8 v;
      #pragma unroll
      for (int j = 0; j < 8; ++j) v[j] = (short)f2bf(inp[(8 * q + j) * 256 + p]);
      *(vs8*)&Xl[p * 64 + (q ^ (p & 7)) * 8] = v;
    }
  }
  // ---- stage W: [e][co][ci^((co&7)<<3)] bf16 (coalesced f32 reads) ----
  for (int i = t; i < COUT * 64 * 9; i += 256) {
    const int co = i / 576;
    const int rem = i - co * 576;
    const int ci = rem / 9;
    const int e = rem - ci * 9;
    Wl[(e * COP + co) * 64 + (ci ^ ((co & 7) << 3))] = f2bf(wsrc[i]);
  }
  if (COP > COUT) {  // zero the co padding rows
    for (int i = t; i < 9 * (COP - COUT) * 64; i += 256) {
      const int e = i >> 9;
      const int r = i & 511;
      Wl[(e * COP + COUT + (r >> 6)) * 64 + (r & 63)] = 0;
    }
  }
  __syncthreads();

  const int w = t >> 6, lane = t & 63;
  const int px = lane & 15, kg = lane >> 4;
  vf4 acc[4][NT];
  #pragma unroll
  for (int mt = 0; mt < 4; ++mt)
    #pragma unroll
    for (int nt = 0; nt < NT; ++nt) acc[mt][nt] = (vf4)0.f;

  for (int e = 0; e < 9; ++e) {
    const int dy = e / 3 - 1, dx = e % 3 - 1;
    const bool xok = (dx == 0) || (dx < 0 ? (px > 0) : (px < 15));
    const int xoff = xok ? dx : 0;
    #pragma unroll
    for (int ks = 0; ks < 2; ++ks) {
      vs8 bf[NT];
      #pragma unroll
      for (int nt = 0; nt < NT; ++nt) {
        const int co = nt * 16 + px;
        bf[nt] = *(const vs8*)&Wl[(e * COP + co) * 64 + (((ks * 4 + kg) ^ (px & 7)) << 3)];
      }
      #pragma unroll
      for (int mt = 0; mt < 4; ++mt) {
        const int yy = 4 * w + mt + dy;
        if (yy < 0 || yy > 15) continue;  // wave-uniform skip
        const int ps = yy * 16 + px + xoff;
        vs8 a = *(const vs8*)&Xl[ps * 64 + (((ks * 4 + kg) ^ (ps & 7)) << 3)];
        if (!xok) a = (vs8)(short)0;
        #pragma unroll
        for (int nt = 0; nt < NT; ++nt)
          acc[mt][nt] = __builtin_amdgcn_mfma_f32_16x16x32_bf16(a, bf[nt], acc[mt][nt], 0, 0, 0);
      }
    }
  }

  // ---- store: C col=lane&15 (co), row=(lane>>4)*4+r (x-coord) -> float4 ----
  #pragma unroll
  for (int mt = 0; mt < 4; ++mt) {
    const int y = 4 * w + mt;
    #pragma unroll
    for (int nt = 0; nt < NT; ++nt) {
      const int co = nt * 16 + px;
      if (co < COUT) {
        const float bv = bias[co];
        vf4 v = acc[mt][nt];
        #pragma unroll
        for (int j = 0; j < 4; ++j) {
          float s = v[j] + bv;
          if (act == 1) s = s > 0.f ? s : 0.01f * s;
          else if (act == 2) s = 1.f / (1.f + __expf(-s));
          v[j] = s;
        }
        *(vf4*)&outp[co * 256 + y * 16 + kg * 4] = v;
      }
    }
  }
}

// ---------------------------------------------------------------------------
// Fused GroupNorm(1,16) + SE-scale + 3x3 conv (16->128) via mfma 32x32x16.
// Block = image n (512 thr, 8 waves); wave owns one 32-pixel M-tile.
// ---------------------------------------------------------------------------
__global__ __launch_bounds__(512) void k_post(
    const float* __restrict__ sol, const float* __restrict__ se,
    const float* __restrict__ gn_w, const float* __restrict__ gn_b,
    const float* __restrict__ pw, const float* __restrict__ pb,
    float* __restrict__ out) {
  __shared__ unsigned short Hl[256 * 24];      // 12 KB ([pix][c], rows 48B)
  __shared__ unsigned short Wp[9 * 128 * 24];  // 55 KB ([e][co][ci])
  __shared__ float rs[8];
  __shared__ float rs2[8];
  const int n = blockIdx.x;
  const int t = threadIdx.x;
  const int w = t >> 6, lane = t & 63;

  // load 8 sol values (coalesced), partial stats
  float v[8];
  {
    const vf4* s4 = (const vf4*)(sol + n * 4096 + 8 * t);
    vf4 a = s4[0], b = s4[1];
    v[0]=a[0];v[1]=a[1];v[2]=a[2];v[3]=a[3];v[4]=b[0];v[5]=b[1];v[6]=b[2];v[7]=b[3];
  }
  float s = 0.f, s2 = 0.f;
  #pragma unroll
  for (int k = 0; k < 8; ++k) { s += v[k]; s2 += v[k] * v[k]; }
  #pragma unroll
  for (int o = 1; o <= 32; o <<= 1) { s += __shfl_xor(s, o, 64); s2 += __shfl_xor(s2, o, 64); }
  if (lane == 0) { rs[w] = s; rs2[w] = s2; }

  // stage W while the reduction settles
  for (int i = t; i < 128 * 16 * 9; i += 512) {
    const int co = i / 144;
    const int rem = i - co * 144;
    const int ci = rem / 9;
    const int e = rem - ci * 9;
    Wp[(e * 128 + co) * 24 + ci] = f2bf(pw[i]);
  }
  __syncthreads();
  float sm = 0.f, sq = 0.f;
  #pragma unroll
  for (int k = 0; k < 8; ++k) { sm += rs[k]; sq += rs2[k]; }
  const float mu = sm * (1.f / 4096.f);
  const float rstd = rsqrtf(sq * (1.f / 4096.f) - mu * mu + 1e-5f);

  // normalize + affine + SE, write H bf16 [pix][c]
  const int c = t >> 5;             // channel (uniform per thread)
  const int p0 = (8 * t) & 255;
  const float sev = se[n * 16 + c];
  const float sc = rstd * gn_w[c] * sev;
  const float of = (gn_b[c] - mu * rstd * gn_w[c]) * sev;
  #pragma unroll
  for (int k = 0; k < 8; ++k) Hl[(p0 + k) * 24 + c] = f2bf(v[k] * sc + of);
  __syncthreads();

  // GEMM: M-tile32 = pixels 32w..32w+31, N = 128 (4 tiles of 32), K = 16
  const int cl = lane & 31, h = lane >> 5;
  const int px = cl & 15, y0 = 2 * w + (cl >> 4);
  vf16 acc[4];
  #pragma unroll
  for (int nt = 0; nt < 4; ++nt) acc[nt] = (vf16)0.f;
  for (int e = 0; e < 9; ++e) {
    const int dy = e / 3 - 1, dx = e % 3 - 1;
    const int yy = y0 + dy, xx = px + dx;
    const bool ok = (yy >= 0 && yy < 16 && xx >= 0 && xx < 16);
    const int ps = ok ? yy * 16 + xx : 0;
    vs8 a = *(const vs8*)&Hl[ps * 24 + h * 8];
    if (!ok) a = (vs8)(short)0;
    #pragma unroll
    for (int nt = 0; nt < 4; ++nt) {
      vs8 bf = *(const vs8*)&Wp[(e * 128 + nt * 32 + cl) * 24 + h * 8];
      acc[nt] = __builtin_amdgcn_mfma_f32_32x32x16_bf16(a, bf, acc[nt], 0, 0, 0);
    }
  }
  // store: col=lane&31 (co), row=(reg&3)+8*(reg>>2)+4*h
  float* op = out + n * 32768;
  #pragma unroll
  for (int nt = 0; nt < 4; ++nt) {
    const int co = nt * 32 + cl;
    const float bv = pb[co];
    #pragma unroll
    for (int rq = 0; rq < 4; ++rq) {
      vf4 vv;
      #pragma unroll
      for (int j = 0; j < 4; ++j) vv[j] = acc[nt][rq * 4 + j] + bv;
      *(vf4*)&op[co * 256 + 32 * w + 8 * rq + 4 * h] = vv;
    }
  }
}

// ---------------------------------------------------------------------------
// Wave-local Chebyshev(NCHEB)-preconditioned CG (unchanged from round 3).
// ---------------------------------------------------------------------------
__global__ __launch_bounds__(64) void k_pcg(
    const float* __restrict__ att, const float* __restrict__ grad,
    float* __restrict__ sol, int maxit, float tol2) {
  const int sys = blockIdx.x >> 1;
  const int wv = blockIdx.x & 1;
  const int l = threadIdx.x;
  const int row = l >> 2, c4 = l & 3;
  const int i0 = 4 * l;

  __shared__ float lds[1024] __attribute__((aligned(16)));
  float4* LDS4 = reinterpret_cast<float4*>(lds);

  const int n = sys >> 2, g = sys & 3;
  const float* ab = att + (n * 40 + g * 10) * 256;
  const float* gb = grad + (n * 40 + g * 10) * 256;

  int era, eda, erb, edb, ec, fa, fb;
  if (wv == 0) { fa = 0; fb = 2; era = 4; eda = 9; erb = 2; edb = 7; ec = 0; }
  else         { fa = 1; fb = 3; era = 8; eda = 5; erb = 6; edb = 3; ec = 1; }

  auto L4 = [](const float* p) { return *reinterpret_cast<const float4*>(p); };
  auto unp = [](float4 v, float* o) { o[0] = v.x; o[1] = v.y; o[2] = v.z; o[3] = v.w; };

  float wLa[4], wRa[4], wUa[4], wDa[4], wXa[4], dga[4], iva[4], rsa[4];
  float wLb[4], wRb[4], wUb[4], wDb[4], wXb[4], dgb[4], ivb[4], rsb[4];

  float rA[4], gA[4], dA[4], hA[4], uA[4] = {0,0,0,0}, vA[4] = {0,0,0,0};
  unp(L4(ab + era * 256 + i0), rA); unp(L4(gb + era * 256 + i0), gA);
  unp(L4(ab + eda * 256 + i0), dA); unp(L4(gb + eda * 256 + i0), hA);
  if (row > 0) { unp(L4(ab + eda * 256 + i0 - 16), uA); unp(L4(gb + eda * 256 + i0 - 16), vA); }
  float rlA = (l > 0) ? ab[era * 256 + i0 - 1] : 0.f;
  float glA = (l > 0) ? gb[era * 256 + i0 - 1] : 0.f;
  float cX[4], gX[4], cU[4] = {0,0,0,0}, gU[4] = {0,0,0,0};
  unp(L4(ab + ec * 256 + i0), cX); unp(L4(gb + ec * 256 + i0), gX);
  float clX = 0.f, glX = 0.f;
  if (wv == 0) { if (l > 0) { clX = ab[ec * 256 + i0 - 1]; glX = gb[ec * 256 + i0 - 1]; } }
  else if (row > 0) { unp(L4(ab + ec * 256 + i0 - 16), cU); unp(L4(gb + ec * 256 + i0 - 16), gU); }

  #pragma unroll
  for (int k = 0; k < 4; ++k) {
    wRa[k] = (k < 3 || c4 < 3) ? rA[k] * rA[k] : 0.f;
    wLa[k] = (k > 0) ? rA[k-1] * rA[k-1] : ((c4 > 0) ? rlA * rlA : 0.f);
    wDa[k] = (row < 15) ? dA[k] * dA[k] : 0.f;
    wUa[k] = (row > 0) ? uA[k] * uA[k] : 0.f;
    float rhs = wRa[k] * gA[k] - wLa[k] * ((k > 0) ? gA[k-1] : glA)
              + wDa[k] * hA[k] - wUa[k] * vA[k];
    float wx, gx;
    if (wv == 0) {
      wx = (k > 0) ? cX[k-1] * cX[k-1] : ((c4 > 0) ? clX * clX : 0.f);
      gx = (k > 0) ? gX[k-1] : glX;
    } else {
      wx = (row > 0) ? cU[k] * cU[k] : 0.f;
      gx = gU[k];
    }
    wXa[k] = wx;
    rhs -= wx * gx;
    rsa[k] = rhs;
    dga[k] = 1e-12f + wRa[k] + wLa[k] + wDa[k] + wUa[k] + wx;
  }

  float rB[4], gB[4], dB[4], hB[4], uB[4] = {0,0,0,0}, vB[4] = {0,0,0,0};
  unp(L4(ab + erb * 256 + i0), rB); unp(L4(gb + erb * 256 + i0), gB);
  unp(L4(ab + edb * 256 + i0), dB); unp(L4(gb + edb * 256 + i0), hB);
  if (row > 0) { unp(L4(ab + edb * 256 + i0 - 16), uB); unp(L4(gb + edb * 256 + i0 - 16), vB); }
  float rlB = (l > 0) ? ab[erb * 256 + i0 - 1] : 0.f;
  float glB = (l > 0) ? gb[erb * 256 + i0 - 1] : 0.f;

  #pragma unroll
  for (int k = 0; k < 4; ++k) {
    wRb[k] = (k < 3 || c4 < 3) ? rB[k] * rB[k] : 0.f;
    wLb[k] = (k > 0) ? rB[k-1] * rB[k-1] : ((c4 > 0) ? rlB * rlB : 0.f);
    wDb[k] = (row < 15) ? dB[k] * dB[k] : 0.f;
    wUb[k] = (row > 0) ? uB[k] * uB[k] : 0.f;
    float wx;
    if (wv == 0) wx = (k < 3 || c4 < 3) ? cX[k] * cX[k] : 0.f;
    else         wx = (row < 15) ? cX[k] * cX[k] : 0.f;
    wXb[k] = wx;
    rsb[k] = wRb[k] * gB[k] - wLb[k] * ((k > 0) ? gB[k-1] : glB)
           + wDb[k] * hB[k] - wUb[k] * vB[k]
           + wx * gX[k];
    dgb[k] = 1e-12f + wRb[k] + wLb[k] + wDb[k] + wUb[k] + wx;
  }

  if (l == 63) {
    float wr = rA[3] * rA[3], wd = dA[3] * dA[3];
    dga[3] += wr + wd;
    rsa[3] += wr * gA[3] + wd * hA[3];
    float wc = cX[3] * cX[3], wrb = rB[3] * rB[3], wdb = dB[3] * dB[3];
    dgb[3] += wc + wrb + wdb;
    rsb[3] += wc * gX[3] + wrb * gB[3] + wdb * hB[3];
  }
  #pragma unroll
  for (int k = 0; k < 4; ++k) { iva[k] = 1.f / dga[k]; ivb[k] = 1.f / dgb[k]; }

  const int upS = (row > 0) ? l - 4 : l;
  const int dnS = (row < 15) ? l + 4 : l;
  const int lF = (l > 0) ? 4 * l - 1 : 0;
  const int rF = (l < 63) ? 4 * l + 4 : 0;

  int pp = 0;
  float ua[4], ub[4], wa[4], wb[4];

  auto spmv = [&](const float (&ia_)[4], const float (&ib_)[4],
                  float (&oa)[4], float (&ob)[4]) {
    const int B = pp << 7;
    const int fB = pp << 9;
    LDS4[B + l]      = make_float4(ia_[0], ia_[1], ia_[2], ia_[3]);
    LDS4[B + 64 + l] = make_float4(ib_[0], ib_[1], ib_[2], ib_[3]);
    float aU[4], aD[4], bU[4], bD[4];
    unp(LDS4[B + upS], aU);      unp(LDS4[B + dnS], aD);
    unp(LDS4[B + 64 + upS], bU); unp(LDS4[B + 64 + dnS], bD);
    float aL = lds[fB + lF], aR = lds[fB + rF];
    float bL = lds[fB + 256 + lF], bR = lds[fB + 256 + rF];
    float uaL[4] = {aL, ia_[0], ia_[1], ia_[2]};
    float uaR[4] = {ia_[1], ia_[2], ia_[3], aR};
    float ubL[4] = {bL, ib_[0], ib_[1], ib_[2]};
    float ubR[4] = {ib_[1], ib_[2], ib_[3], bR};
    #pragma unroll
    for (int k = 0; k < 4; ++k) {
      float cA = (wv == 0) ? ubL[k] : bU[k];
      float cB = (wv == 0) ? uaR[k] : aD[k];
      oa[k] = dga[k] * ia_[k] - wLa[k] * uaL[k] - wRa[k] * uaR[k]
            - wUa[k] * aU[k] - wDa[k] * aD[k] - wXa[k] * cA;
      ob[k] = dgb[k] * ib_[k] - wLb[k] * ubL[k] - wRb[k] * ubR[k]
            - wUb[k] * bU[k] - wDb[k] * bD[k] - wXb[k] * cB;
    }
    pp ^= 1;
  };

  constexpr float lo = 0.04f, hi = 2.0f;
  constexpr float th = (hi + lo) * 0.5f, dl = (hi - lo) * 0.5f, s1 = th / dl;

  float xa[4] = {0,0,0,0}, xb[4] = {0,0,0,0};
  float ra_[4], rb_[4], pa[4] = {0,0,0,0}, pb_[4] = {0,0,0,0};
  float sa[4] = {0,0,0,0}, sb[4] = {0,0,0,0};
  #pragma unroll
  for (int k = 0; k < 4; ++k) { ra_[k] = rsa[k]; rb_[k] = rsb[k]; }

  auto cheb = [&]() {
    float da_[4], db_[4], ta[4], tb[4], qa[4], qb[4];
    #pragma unroll
    for (int k = 0; k < 4; ++k) {
      da_[k] = (1.0f / th) * iva[k] * ra_[k];
      db_[k] = (1.0f / th) * ivb[k] * rb_[k];
      ua[k] = da_[k]; ub[k] = db_[k];
    }
    spmv(da_, db_, ta, tb);
    #pragma unroll
    for (int k = 0; k < 4; ++k) {
      wa[k] = ta[k]; wb[k] = tb[k];
      qa[k] = ra_[k] - ta[k]; qb[k] = rb_[k] - tb[k];
    }
    float rho = 1.0f / s1;
    #pragma unroll
    for (int j = 1; j < NCHEB; ++j) {
      float rho2 = 1.0f / (2.0f * s1 - rho);
      float c1 = rho2 * rho, c2 = 2.0f * rho2 / dl;
      #pragma unroll
      for (int k = 0; k < 4; ++k) {
        da_[k] = c1 * da_[k] + c2 * iva[k] * qa[k];
        db_[k] = c1 * db_[k] + c2 * ivb[k] * qb[k];
        ua[k] += da_[k]; ub[k] += db_[k];
      }
      spmv(da_, db_, ta, tb);
      #pragma unroll
      for (int k = 0; k < 4; ++k) {
        wa[k] += ta[k]; wb[k] += tb[k];
        qa[k] -= ta[k]; qb[k] -= tb[k];
      }
      rho = rho2;
    }
  };

  float gamma, delta;
  auto dots = [&]() {
    float gp = 0.f, dp = 0.f;
    #pragma unroll
    for (int k = 0; k < 4; ++k) {
      gp += ra_[k] * ua[k] + rb_[k] * ub[k];
      dp += wa[k] * ua[k] + wb[k] * ub[k];
    }
    #pragma unroll
    for (int o = 1; o <= 32; o <<= 1) {
      gp += __shfl_xor(gp, o, 64);
      dp += __shfl_xor(dp, o, 64);
    }
    gamma = gp; delta = dp;
  };

  cheb();
  dots();
  const float thresh = tol2 * gamma;
  float gamma_old = gamma, alpha_old = 1.f;

  for (int it = 0; it < maxit && gamma > thresh; ++it) {
    float beta = (it == 0) ? 0.f : gamma / gamma_old;
    float alpha = (it == 0) ? gamma / delta
                            : gamma / (delta - beta * gamma / alpha_old);
    #pragma unroll
    for (int k = 0; k < 4; ++k) {
      pa[k] = ua[k] + beta * pa[k];   pb_[k] = ub[k] + beta * pb_[k];
      sa[k] = wa[k] + beta * sa[k];   sb[k] = wb[k] + beta * sb[k];
      xa[k] += alpha * pa[k];         xb[k] += alpha * pb_[k];
      ra_[k] -= alpha * sa[k];        rb_[k] -= alpha * sb[k];
    }
    gamma_old = gamma; alpha_old = alpha;
    cheb();
    dots();
  }

  float4* sol4 = reinterpret_cast<float4*>(sol);
  sol4[sys * 256 + fa * 64 + l] = make_float4(xa[0], xa[1], xa[2], xa[3]);
  sol4[sys * 256 + fb * 64 + l] = make_float4(xb[0], xb[1], xb[2], xb[3]);
}

extern "C" void kernel_launch(void* const* d_in, const int* in_sizes, int n_in,
                              void* d_out, int out_size, void* d_ws, size_t ws_size,
                              hipStream_t stream) {
  const float* x       = (const float*)d_in[0];
  const float* grad_w1 = (const float*)d_in[1];
  const float* grad_b1 = (const float*)d_in[2];
  const float* grad_w2 = (const float*)d_in[3];
  const float* grad_b2 = (const float*)d_in[4];
  const float* att_w1  = (const float*)d_in[5];
  const float* att_b1  = (const float*)d_in[6];
  const float* att_w2  = (const float*)d_in[7];
  const float* att_b2  = (const float*)d_in[8];
  const float* se_w1   = (const float*)d_in[9];
  const float* se_b1   = (const float*)d_in[10];
  const float* se_w2   = (const float*)d_in[11];
  const float* se_b2   = (const float*)d_in[12];
  const float* gn_w    = (const float*)d_in[13];
  const float* gn_b    = (const float*)d_in[14];
  const float* post_w  = (const float*)d_in[15];
  const float* post_b  = (const float*)d_in[16];
  float* out = (float*)d_out;
  float* ws = (float*)d_ws;

  float* t1    = ws;                // 65536 (grad conv1 out)
  float* t2    = ws + 65536;        // 65536 (att conv1 out)
  float* gradb = ws + 131072;       // 40960
  float* attb  = ws + 172032;       // 40960
  float* seb   = ws + 212992;       // 64
  float* solb  = ws;                // 16384 (reuses t1 after conv2)

  // conv1 (both branches, lrelu) + SE branch folded into blocks 8..11
  k_conv<64, 64, 4, true><<<12, 256, 0, stream>>>(
      x, x, grad_w1, grad_b1, att_w1, att_b1, t1, t2, 1, 1,
      x, se_w1, se_b1, se_w2, se_b2, seb);
  // conv2: grad (linear), att (sigmoid)
  k_conv<40, 48, 3, false><<<8, 256, 0, stream>>>(
      t1, t2, grad_w2, grad_b2, att_w2, att_b2, gradb, attb, 0, 2,
      nullptr, nullptr, nullptr, nullptr, nullptr, nullptr);
  k_pcg<<<32, 64, 0, stream>>>(attb, gradb, solb, 300, 1e-10f);
  k_post<<<4, 512, 0, stream>>>(solb, seb, gn_w, gn_b, post_w, post_b, out);
}

// Round 5
// 70.498 us; speedup vs baseline: 4.5711x; 1.1942x over previous
//
#include <hip/hip_runtime.h>

#define NCHEB 8

typedef __attribute__((ext_vector_type(8))) short vs8;
typedef __attribute__((ext_vector_type(4))) float vf4;
typedef __attribute__((ext_vector_type(16))) float vf16;

__device__ __forceinline__ unsigned short f2bf(float f) {
  union { float f; unsigned int u; } x; x.f = f;
  unsigned int r = (x.u + 0x7FFFu + ((x.u >> 16) & 1u)) >> 16;
  return (unsigned short)r;
}

// ---------------------------------------------------------------------------
// MFMA 3x3 SAME conv on 16x16 images as 9 shifted GEMMs (bf16 in, f32 acc).
// Co-tile split: block = (branch, image, co-tile of 16). 4 waves; wave owns
// 4 M-tiles of 16 pixels, 1 N-tile of 16 co.
// X in LDS pixel-major [pix][ci], XOR chunk swizzle; W slice [e][col][ci].
// SE==true: blocks >= 8*TILES run the squeeze-excite branch.
// ---------------------------------------------------------------------------
template<int COUT, int TILES, bool SE>
__global__ __launch_bounds__(256) void k_conv(
    const float* __restrict__ inA, const float* __restrict__ inB,
    const float* __restrict__ wA, const float* __restrict__ bA,
    const float* __restrict__ wB, const float* __restrict__ bB,
    float* __restrict__ outA, float* __restrict__ outB,
    int actA, int actB,
    const float* __restrict__ x,
    const float* __restrict__ sw1, const float* __restrict__ sb1,
    const float* __restrict__ sw2, const float* __restrict__ sb2,
    float* __restrict__ seo) {
  __shared__ unsigned short Xl[256 * 64];   // 32 KB
  __shared__ unsigned short Wl[9 * 16 * 64]; // 18 KB
  __shared__ float sp[64];
  __shared__ float sh1[32];
  const int b = blockIdx.x;
  const int t = threadIdx.x;

  if (SE && b >= 8 * TILES) {  // ---- squeeze-excite branch (4 blocks) ----
    const int n = b - 8 * TILES;
    const int c = t >> 2, part = t & 3;
    const float* xp = x + (n * 64 + c) * 256 + part * 64;
    float s = 0.f;
    for (int k = 0; k < 64; ++k) s += xp[k];
    s += __shfl_xor(s, 1, 64);
    s += __shfl_xor(s, 2, 64);
    if (part == 0) sp[c] = s * (1.f / 256.f);
    __syncthreads();
    if (t < 32) {
      float a = sb1[t];
      for (int k = 0; k < 64; ++k) a += sw1[t * 64 + k] * sp[k];
      sh1[t] = a > 0.f ? a : 0.01f * a;
    }
    __syncthreads();
    if (t < 16) {
      float a = sb2[t];
      for (int k = 0; k < 32; ++k) a += sw2[t * 32 + k] * sh1[k];
      seo[n * 16 + t] = 1.f / (1.f + __expf(-a));
    }
    return;
  }

  const int n = b & 3;
  const int q = b >> 2;                 // 0 .. 2*TILES-1
  const int br = (q >= TILES) ? 1 : 0;
  const int ct = q - br * TILES;
  const int co0 = ct * 16;
  const float* inp = (br ? inB : inA) + n * 64 * 256;
  const float* wsrc = br ? wB : wA;
  const float* bias = br ? bB : bA;
  float* outp = (br ? outB : outA) + n * COUT * 256;
  const int act = br ? actB : actA;

  // ---- stage X: [pix][ci] bf16, chunk c' = chunk ^ (pix&7) ----
  {
    const int p = t;
    #pragma unroll
    for (int q8 = 0; q8 < 8; ++q8) {
      vs8 v;
      #pragma unroll
      for (int j = 0; j < 8; ++j) v[j] = (short)f2bf(inp[(8 * q8 + j) * 256 + p]);
      *(vs8*)&Xl[p * 64 + ((q8 ^ (p & 7)) << 3)] = v;
    }
  }
  // ---- stage W slice: [e][col][ci^((col&7)<<3)], division-free ----
  {
    const int col = t >> 4;             // 0..15 local co
    const int sub = t & 15;
    const int co = co0 + col;
    if (co < COUT) {
      const float* wp = wsrc + (co * 64 + sub * 4) * 9;
      #pragma unroll
      for (int cc = 0; cc < 4; ++cc) {
        const int ci = sub * 4 + cc;
        #pragma unroll
        for (int e = 0; e < 9; ++e)
          Wl[(e * 16 + col) * 64 + (ci ^ ((col & 7) << 3))] = f2bf(wp[cc * 9 + e]);
      }
    } else {
      #pragma unroll
      for (int cc = 0; cc < 4; ++cc) {
        const int ci = sub * 4 + cc;
        #pragma unroll
        for (int e = 0; e < 9; ++e)
          Wl[(e * 16 + col) * 64 + (ci ^ ((col & 7) << 3))] = 0;
      }
    }
  }
  __syncthreads();

  const int w = t >> 6, lane = t & 63;
  const int px = lane & 15, kg = lane >> 4;
  vf4 acc[4];
  #pragma unroll
  for (int mt = 0; mt < 4; ++mt) acc[mt] = (vf4)0.f;

  for (int e = 0; e < 9; ++e) {
    const int dy = e / 3 - 1, dx = e % 3 - 1;
    const bool xok = (dx == 0) || (dx < 0 ? (px > 0) : (px < 15));
    const int xoff = xok ? dx : 0;
    #pragma unroll
    for (int ks = 0; ks < 2; ++ks) {
      vs8 bf = *(const vs8*)&Wl[(e * 16 + px) * 64 + (((ks * 4 + kg) ^ (px & 7)) << 3)];
      #pragma unroll
      for (int mt = 0; mt < 4; ++mt) {
        const int yy = 4 * w + mt + dy;
        if (yy < 0 || yy > 15) continue;  // wave-uniform skip
        const int ps = yy * 16 + px + xoff;
        vs8 a = *(const vs8*)&Xl[ps * 64 + (((ks * 4 + kg) ^ (ps & 7)) << 3)];
        if (!xok) a = (vs8)(short)0;
        acc[mt] = __builtin_amdgcn_mfma_f32_16x16x32_bf16(a, bf, acc[mt], 0, 0, 0);
      }
    }
  }

  // ---- store: C col=lane&15 (co), row=(lane>>4)*4+j (pixel x) ----
  const int co = co0 + px;
  if (co < COUT) {
    const float bv = bias[co];
    #pragma unroll
    for (int mt = 0; mt < 4; ++mt) {
      const int y = 4 * w + mt;
      vf4 v = acc[mt];
      #pragma unroll
      for (int j = 0; j < 4; ++j) {
        float s = v[j] + bv;
        if (act == 1) s = s > 0.f ? s : 0.01f * s;
        else if (act == 2) s = 1.f / (1.f + __expf(-s));
        v[j] = s;
      }
      *(vf4*)&outp[co * 256 + y * 16 + kg * 4] = v;
    }
  }
}

// ---------------------------------------------------------------------------
// Fused GroupNorm(1,16) + SE-scale + 3x3 conv (16->128) via mfma 32x32x16.
// Block = image n (512 thr, 8 waves); wave owns one 32-pixel M-tile.
// ---------------------------------------------------------------------------
__global__ __launch_bounds__(512) void k_post(
    const float* __restrict__ sol, const float* __restrict__ se,
    const float* __restrict__ gn_w, const float* __restrict__ gn_b,
    const float* __restrict__ pw, const float* __restrict__ pb,
    float* __restrict__ out) {
  __shared__ unsigned short Hl[256 * 24];      // 12 KB ([pix][c], rows 48B)
  __shared__ unsigned short Wp[9 * 128 * 24];  // 55 KB ([e][co][ci])
  __shared__ float rs[8];
  __shared__ float rs2[8];
  const int n = blockIdx.x;
  const int t = threadIdx.x;
  const int w = t >> 6, lane = t & 63;

  float v[8];
  {
    const vf4* s4 = (const vf4*)(sol + n * 4096 + 8 * t);
    vf4 a = s4[0], b = s4[1];
    v[0]=a[0];v[1]=a[1];v[2]=a[2];v[3]=a[3];v[4]=b[0];v[5]=b[1];v[6]=b[2];v[7]=b[3];
  }
  float s = 0.f, s2 = 0.f;
  #pragma unroll
  for (int k = 0; k < 8; ++k) { s += v[k]; s2 += v[k] * v[k]; }
  #pragma unroll
  for (int o = 1; o <= 32; o <<= 1) { s += __shfl_xor(s, o, 64); s2 += __shfl_xor(s2, o, 64); }
  if (lane == 0) { rs[w] = s; rs2[w] = s2; }

  // stage W (division-free): co = t>>2, 4 subthreads cover 16 ci
  {
    const int co = t >> 2, sub = t & 3;
    const float* wp0 = pw + (co * 16 + sub * 4) * 9;
    #pragma unroll
    for (int cc = 0; cc < 4; ++cc) {
      const int ci = sub * 4 + cc;
      #pragma unroll
      for (int e = 0; e < 9; ++e)
        Wp[(e * 128 + co) * 24 + ci] = f2bf(wp0[cc * 9 + e]);
    }
  }
  __syncthreads();
  float sm = 0.f, sq = 0.f;
  #pragma unroll
  for (int k = 0; k < 8; ++k) { sm += rs[k]; sq += rs2[k]; }
  const float mu = sm * (1.f / 4096.f);
  const float rstd = rsqrtf(sq * (1.f / 4096.f) - mu * mu + 1e-5f);

  const int c = t >> 5;
  const int p0 = (8 * t) & 255;
  const float sev = se[n * 16 + c];
  const float sc = rstd * gn_w[c] * sev;
  const float of = (gn_b[c] - mu * rstd * gn_w[c]) * sev;
  #pragma unroll
  for (int k = 0; k < 8; ++k) Hl[(p0 + k) * 24 + c] = f2bf(v[k] * sc + of);
  __syncthreads();

  const int cl = lane & 31, h = lane >> 5;
  const int px = cl & 15, y0 = 2 * w + (cl >> 4);
  vf16 acc[4];
  #pragma unroll
  for (int nt = 0; nt < 4; ++nt) acc[nt] = (vf16)0.f;
  for (int e = 0; e < 9; ++e) {
    const int dy = e / 3 - 1, dx = e % 3 - 1;
    const int yy = y0 + dy, xx = px + dx;
    const bool ok = (yy >= 0 && yy < 16 && xx >= 0 && xx < 16);
    const int ps = ok ? yy * 16 + xx : 0;
    vs8 a = *(const vs8*)&Hl[ps * 24 + h * 8];
    if (!ok) a = (vs8)(short)0;
    #pragma unroll
    for (int nt = 0; nt < 4; ++nt) {
      vs8 bf = *(const vs8*)&Wp[(e * 128 + nt * 32 + cl) * 24 + h * 8];
      acc[nt] = __builtin_amdgcn_mfma_f32_32x32x16_bf16(a, bf, acc[nt], 0, 0, 0);
    }
  }
  float* op = out + n * 32768;
  #pragma unroll
  for (int nt = 0; nt < 4; ++nt) {
    const int co = nt * 32 + cl;
    const float bv = pb[co];
    #pragma unroll
    for (int rq = 0; rq < 4; ++rq) {
      vf4 vv;
      #pragma unroll
      for (int j = 0; j < 4; ++j) vv[j] = acc[nt][rq * 4 + j] + bv;
      *(vf4*)&op[co * 256 + 32 * w + 8 * rq + 4 * h] = vv;
    }
  }
}

// ---------------------------------------------------------------------------
// Wave-local Chebyshev(NCHEB)-preconditioned CG, shuffle-based SpMV
// (no LDS, no barriers). One 64-lane wave per (system, component).
// ---------------------------------------------------------------------------
__global__ __launch_bounds__(64) void k_pcg(
    const float* __restrict__ att, const float* __restrict__ grad,
    float* __restrict__ sol, int maxit, float tol2) {
  const int sys = blockIdx.x >> 1;
  const int wv = blockIdx.x & 1;
  const int l = threadIdx.x;
  const int row = l >> 2, c4 = l & 3;
  const int i0 = 4 * l;

  const int n = sys >> 2, g = sys & 3;
  const float* ab = att + (n * 40 + g * 10) * 256;
  const float* gb = grad + (n * 40 + g * 10) * 256;

  int era, eda, erb, edb, ec, fa, fb;
  if (wv == 0) { fa = 0; fb = 2; era = 4; eda = 9; erb = 2; edb = 7; ec = 0; }
  else         { fa = 1; fb = 3; era = 8; eda = 5; erb = 6; edb = 3; ec = 1; }

  auto L4 = [](const float* p) { return *reinterpret_cast<const float4*>(p); };
  auto unp = [](float4 v, float* o) { o[0] = v.x; o[1] = v.y; o[2] = v.z; o[3] = v.w; };

  float wLa[4], wRa[4], wUa[4], wDa[4], wXa[4], dga[4], iva[4], rsa[4];
  float wLb[4], wRb[4], wUb[4], wDb[4], wXb[4], dgb[4], ivb[4], rsb[4];

  float rA[4], gA[4], dA[4], hA[4], uA[4] = {0,0,0,0}, vA[4] = {0,0,0,0};
  unp(L4(ab + era * 256 + i0), rA); unp(L4(gb + era * 256 + i0), gA);
  unp(L4(ab + eda * 256 + i0), dA); unp(L4(gb + eda * 256 + i0), hA);
  if (row > 0) { unp(L4(ab + eda * 256 + i0 - 16), uA); unp(L4(gb + eda * 256 + i0 - 16), vA); }
  float rlA = (l > 0) ? ab[era * 256 + i0 - 1] : 0.f;
  float glA = (l > 0) ? gb[era * 256 + i0 - 1] : 0.f;
  float cX[4], gX[4], cU[4] = {0,0,0,0}, gU[4] = {0,0,0,0};
  unp(L4(ab + ec * 256 + i0), cX); unp(L4(gb + ec * 256 + i0), gX);
  float clX = 0.f, glX = 0.f;
  if (wv == 0) { if (l > 0) { clX = ab[ec * 256 + i0 - 1]; glX = gb[ec * 256 + i0 - 1]; } }
  else if (row > 0) { unp(L4(ab + ec * 256 + i0 - 16), cU); unp(L4(gb + ec * 256 + i0 - 16), gU); }

  #pragma unroll
  for (int k = 0; k < 4; ++k) {
    wRa[k] = (k < 3 || c4 < 3) ? rA[k] * rA[k] : 0.f;
    wLa[k] = (k > 0) ? rA[k-1] * rA[k-1] : ((c4 > 0) ? rlA * rlA : 0.f);
    wDa[k] = (row < 15) ? dA[k] * dA[k] : 0.f;
    wUa[k] = (row > 0) ? uA[k] * uA[k] : 0.f;
    float rhs = wRa[k] * gA[k] - wLa[k] * ((k > 0) ? gA[k-1] : glA)
              + wDa[k] * hA[k] - wUa[k] * vA[k];
    float wx, gx;
    if (wv == 0) {
      wx = (k > 0) ? cX[k-1] * cX[k-1] : ((c4 > 0) ? clX * clX : 0.f);
      gx = (k > 0) ? gX[k-1] : glX;
    } else {
      wx = (row > 0) ? cU[k] * cU[k] : 0.f;
      gx = gU[k];
    }
    wXa[k] = wx;
    rhs -= wx * gx;
    rsa[k] = rhs;
    dga[k] = 1e-12f + wRa[k] + wLa[k] + wDa[k] + wUa[k] + wx;
  }

  float rB[4], gB[4], dB[4], hB[4], uB[4] = {0,0,0,0}, vB[4] = {0,0,0,0};
  unp(L4(ab + erb * 256 + i0), rB); unp(L4(gb + erb * 256 + i0), gB);
  unp(L4(ab + edb * 256 + i0), dB); unp(L4(gb + edb * 256 + i0), hB);
  if (row > 0) { unp(L4(ab + edb * 256 + i0 - 16), uB); unp(L4(gb + edb * 256 + i0 - 16), vB); }
  float rlB = (l > 0) ? ab[erb * 256 + i0 - 1] : 0.f;
  float glB = (l > 0) ? gb[erb * 256 + i0 - 1] : 0.f;

  #pragma unroll
  for (int k = 0; k < 4; ++k) {
    wRb[k] = (k < 3 || c4 < 3) ? rB[k] * rB[k] : 0.f;
    wLb[k] = (k > 0) ? rB[k-1] * rB[k-1] : ((c4 > 0) ? rlB * rlB : 0.f);
    wDb[k] = (row < 15) ? dB[k] * dB[k] : 0.f;
    wUb[k] = (row > 0) ? uB[k] * uB[k] : 0.f;
    float wx;
    if (wv == 0) wx = (k < 3 || c4 < 3) ? cX[k] * cX[k] : 0.f;
    else         wx = (row < 15) ? cX[k] * cX[k] : 0.f;
    wXb[k] = wx;
    rsb[k] = wRb[k] * gB[k] - wLb[k] * ((k > 0) ? gB[k-1] : glB)
           + wDb[k] * hB[k] - wUb[k] * vB[k]
           + wx * gX[k];
    dgb[k] = 1e-12f + wRb[k] + wLb[k] + wDb[k] + wUb[k] + wx;
  }

  if (l == 63) {
    float wr = rA[3] * rA[3], wd = dA[3] * dA[3];
    dga[3] += wr + wd;
    rsa[3] += wr * gA[3] + wd * hA[3];
    float wc = cX[3] * cX[3], wrb = rB[3] * rB[3], wdb = dB[3] * dB[3];
    dgb[3] += wc + wrb + wdb;
    rsb[3] += wc * gX[3] + wrb * gB[3] + wdb * hB[3];
  }
  #pragma unroll
  for (int k = 0; k < 4; ++k) { iva[k] = 1.f / dga[k]; ivb[k] = 1.f / dgb[k]; }

  float ua[4], ub[4], wa[4], wb[4];

  // SpMV via wave shuffles: 20 independent cross-lane fetches, no LDS.
  auto spmv = [&](const float (&ia_)[4], const float (&ib_)[4],
                  float (&oa)[4], float (&ob)[4]) {
    float aU[4], aD[4], bU[4], bD[4];
    #pragma unroll
    for (int k = 0; k < 4; ++k) {
      aU[k] = __shfl_up(ia_[k], 4, 64);
      aD[k] = __shfl_down(ia_[k], 4, 64);
      bU[k] = __shfl_up(ib_[k], 4, 64);
      bD[k] = __shfl_down(ib_[k], 4, 64);
    }
    float aL = __shfl_up(ia_[3], 1, 64);
    float aR = __shfl_down(ia_[0], 1, 64);
    float bL = __shfl_up(ib_[3], 1, 64);
    float bR = __shfl_down(ib_[0], 1, 64);
    float uaL[4] = {aL, ia_[0], ia_[1], ia_[2]};
    float uaR[4] = {ia_[1], ia_[2], ia_[3], aR};
    float ubL[4] = {bL, ib_[0], ib_[1], ib_[2]};
    float ubR[4] = {ib_[1], ib_[2], ib_[3], bR};
    #pragma unroll
    for (int k = 0; k < 4; ++k) {
      float cA = (wv == 0) ? ubL[k] : bU[k];
      float cB = (wv == 0) ? uaR[k] : aD[k];
      oa[k] = dga[k] * ia_[k] - wLa[k] * uaL[k] - wRa[k] * uaR[k]
            - wUa[k] * aU[k] - wDa[k] * aD[k] - wXa[k] * cA;
      ob[k] = dgb[k] * ib_[k] - wLb[k] * ubL[k] - wRb[k] * ubR[k]
            - wUb[k] * bU[k] - wDb[k] * bD[k] - wXb[k] * cB;
    }
  };

  constexpr float lo = 0.04f, hi = 2.0f;
  constexpr float th = (hi + lo) * 0.5f, dl = (hi - lo) * 0.5f, s1 = th / dl;

  float xa[4] = {0,0,0,0}, xb[4] = {0,0,0,0};
  float ra_[4], rb_[4], pa[4] = {0,0,0,0}, pb_[4] = {0,0,0,0};
  float sa[4] = {0,0,0,0}, sb[4] = {0,0,0,0};
  #pragma unroll
  for (int k = 0; k < 4; ++k) { ra_[k] = rsa[k]; rb_[k] = rsb[k]; }

  auto cheb = [&]() {
    float da_[4], db_[4], ta[4], tb[4], qa[4], qb[4];
    #pragma unroll
    for (int k = 0; k < 4; ++k) {
      da_[k] = (1.0f / th) * iva[k] * ra_[k];
      db_[k] = (1.0f / th) * ivb[k] * rb_[k];
      ua[k] = da_[k]; ub[k] = db_[k];
    }
    spmv(da_, db_, ta, tb);
    #pragma unroll
    for (int k = 0; k < 4; ++k) {
      wa[k] = ta[k]; wb[k] = tb[k];
      qa[k] = ra_[k] - ta[k]; qb[k] = rb_[k] - tb[k];
    }
    float rho = 1.0f / s1;
    #pragma unroll
    for (int j = 1; j < NCHEB; ++j) {
      float rho2 = 1.0f / (2.0f * s1 - rho);
      float c1 = rho2 * rho, c2 = 2.0f * rho2 / dl;
      #pragma unroll
      for (int k = 0; k < 4; ++k) {
        da_[k] = c1 * da_[k] + c2 * iva[k] * qa[k];
        db_[k] = c1 * db_[k] + c2 * ivb[k] * qb[k];
        ua[k] += da_[k]; ub[k] += db_[k];
      }
      spmv(da_, db_, ta, tb);
      #pragma unroll
      for (int k = 0; k < 4; ++k) {
        wa[k] += ta[k]; wb[k] += tb[k];
        qa[k] -= ta[k]; qb[k] -= tb[k];
      }
      rho = rho2;
    }
  };

  float gamma, delta;
  auto dots = [&]() {
    float gp = 0.f, dp = 0.f;
    #pragma unroll
    for (int k = 0; k < 4; ++k) {
      gp += ra_[k] * ua[k] + rb_[k] * ub[k];
      dp += wa[k] * ua[k] + wb[k] * ub[k];
    }
    #pragma unroll
    for (int o = 1; o <= 32; o <<= 1) {
      gp += __shfl_xor(gp, o, 64);
      dp += __shfl_xor(dp, o, 64);
    }
    gamma = gp; delta = dp;
  };

  cheb();
  dots();
  const float thresh = tol2 * gamma;
  float gamma_old = gamma, alpha_old = 1.f;

  for (int it = 0; it < maxit && gamma > thresh; ++it) {
    float beta = (it == 0) ? 0.f : gamma / gamma_old;
    float alpha = (it == 0) ? gamma / delta
                            : gamma / (delta - beta * gamma / alpha_old);
    #pragma unroll
    for (int k = 0; k < 4; ++k) {
      pa[k] = ua[k] + beta * pa[k];   pb_[k] = ub[k] + beta * pb_[k];
      sa[k] = wa[k] + beta * sa[k];   sb[k] = wb[k] + beta * sb[k];
      xa[k] += alpha * pa[k];         xb[k] += alpha * pb_[k];
      ra_[k] -= alpha * sa[k];        rb_[k] -= alpha * sb[k];
    }
    gamma_old = gamma; alpha_old = alpha;
    cheb();
    dots();
  }

  float4* sol4 = reinterpret_cast<float4*>(sol);
  sol4[sys * 256 + fa * 64 + l] = make_float4(xa[0], xa[1], xa[2], xa[3]);
  sol4[sys * 256 + fb * 64 + l] = make_float4(xb[0], xb[1], xb[2], xb[3]);
}

extern "C" void kernel_launch(void* const* d_in, const int* in_sizes, int n_in,
                              void* d_out, int out_size, void* d_ws, size_t ws_size,
                              hipStream_t stream) {
  const float* x       = (const float*)d_in[0];
  const float* grad_w1 = (const float*)d_in[1];
  const float* grad_b1 = (const float*)d_in[2];
  const float* grad_w2 = (const float*)d_in[3];
  const float* grad_b2 = (const float*)d_in[4];
  const float* att_w1  = (const float*)d_in[5];
  const float* att_b1  = (const float*)d_in[6];
  const float* att_w2  = (const float*)d_in[7];
  const float* att_b2  = (const float*)d_in[8];
  const float* se_w1   = (const float*)d_in[9];
  const float* se_b1   = (const float*)d_in[10];
  const float* se_w2   = (const float*)d_in[11];
  const float* se_b2   = (const float*)d_in[12];
  const float* gn_w    = (const float*)d_in[13];
  const float* gn_b    = (const float*)d_in[14];
  const float* post_w  = (const float*)d_in[15];
  const float* post_b  = (const float*)d_in[16];
  float* out = (float*)d_out;
  float* ws = (float*)d_ws;

  float* t1    = ws;                // 65536 (grad conv1 out)
  float* t2    = ws + 65536;        // 65536 (att conv1 out)
  float* gradb = ws + 131072;       // 40960
  float* attb  = ws + 172032;       // 40960
  float* seb   = ws + 212992;       // 64
  float* solb  = ws;                // 16384 (reuses t1 after conv2)

  // conv1: 2 branches x 4 images x 4 co-tiles = 32 blocks + 4 SE blocks
  k_conv<64, 4, true><<<36, 256, 0, stream>>>(
      x, x, grad_w1, grad_b1, att_w1, att_b1, t1, t2, 1, 1,
      x, se_w1, se_b1, se_w2, se_b2, seb);
  // conv2: 2 x 4 x 3 co-tiles = 24 blocks
  k_conv<40, 3, false><<<24, 256, 0, stream>>>(
      t1, t2, grad_w2, grad_b2, att_w2, att_b2, gradb, attb, 0, 2,
      nullptr, nullptr, nullptr, nullptr, nullptr, nullptr);
  k_pcg<<<32, 64, 0, stream>>>(attb, gradb, solb, 300, 1e-8f);
  k_post<<<4, 512, 0, stream>>>(solb, seb, gn_w, gn_b, post_w, post_b, out);
}